// Round 10
// baseline (924.060 us; speedup 1.0000x reference)
//
#include <hip/hip_runtime.h>
#include <hip/hip_bf16.h>
#include <math.h>

#define C 256
#define NROWS (64*56*56)   // 200704
#define EPSV 0.001f
#define TRI(i) (((i)*((i)+1))>>1)

typedef __attribute__((ext_vector_type(8))) short bf16x8;
typedef __attribute__((ext_vector_type(4))) float f32x4;
typedef __attribute__((ext_vector_type(4))) unsigned short u16x4;
#define MFMA16 __builtin_amdgcn_mfma_f32_16x16x32_bf16

// padded packed-lower-triangle layout: row i starts at PAD(i), rows rounded to 4 floats
__device__ __forceinline__ int PAD(int i) {
    int a = i >> 2, b = i & 3;
    return ((a + 1) * (2 * a + b)) << 2;
}
// total size: PAD(255)+256 = 33280 floats

__device__ __forceinline__ float bcastf(float v, int l) {
    return __int_as_float(__builtin_amdgcn_readlane(__float_as_int(v), l));
}

// split two f32 into packed bf16 hi (truncated) and bf16 lo (residual)
__device__ __forceinline__ void split2(float v0, float v1, unsigned& hi, unsigned& lo) {
    unsigned b0 = __float_as_uint(v0), b1 = __float_as_uint(v1);
    hi = (b0 >> 16) | (b1 & 0xFFFF0000u);
    float l0 = v0 - __uint_as_float(b0 & 0xFFFF0000u);
    float l1 = v1 - __uint_as_float(b1 & 0xFFFF0000u);
    lo = (__float_as_uint(l0) >> 16) | (__float_as_uint(l1) & 0xFFFF0000u);
}

// ws layout (floats):
//  [0,256)          : channel sums
//  [256,512)        : biasacc
//  [512,524800)     : S8 = 8 copies of S partials (8*65536)
//  [524800,558080)  : Lg  = factored triangle
//  [558080,590848)  : Wghi (65536 bf16 as ushort)
//  [590848,623616)  : Wglo

// ---------------- K2: S = X^T X via bf16-split MFMA + fused channel sums ----------------
template<int W>
__device__ __forceinline__ void cov_step(f32x4* acc, const unsigned* lh, const unsigned* ll,
                                         int m, int kg) {
    constexpr int R0 = W, R1 = 7 - W, R2 = 8 + W, R3 = 15 - W;
    constexpr int O0 = 0, O1 = W + 1, O2 = 9, O3 = 18 + W;
    bf16x8 ah[4], al[4];
    {
        int o0 = (R0 * 16 + m) * 20 + kg * 4;
        int o1 = (R1 * 16 + m) * 20 + kg * 4;
        int o2 = (R2 * 16 + m) * 20 + kg * 4;
        int o3 = (R3 * 16 + m) * 20 + kg * 4;
        ah[0] = *(const bf16x8*)&lh[o0]; al[0] = *(const bf16x8*)&ll[o0];
        ah[1] = *(const bf16x8*)&lh[o1]; al[1] = *(const bf16x8*)&ll[o1];
        ah[2] = *(const bf16x8*)&lh[o2]; al[2] = *(const bf16x8*)&ll[o2];
        ah[3] = *(const bf16x8*)&lh[o3]; al[3] = *(const bf16x8*)&ll[o3];
    }
#pragma unroll
    for (int c = 0; c <= R3; ++c) {
        int o = (c * 16 + m) * 20 + kg * 4;
        bf16x8 bh = *(const bf16x8*)&lh[o];
        bf16x8 bl = *(const bf16x8*)&ll[o];
        if (c <= R0) {
            acc[O0 + c] = MFMA16(ah[0], bh, acc[O0 + c], 0, 0, 0);
            acc[O0 + c] = MFMA16(ah[0], bl, acc[O0 + c], 0, 0, 0);
            acc[O0 + c] = MFMA16(al[0], bh, acc[O0 + c], 0, 0, 0);
        }
        if (c <= R1) {
            acc[O1 + c] = MFMA16(ah[1], bh, acc[O1 + c], 0, 0, 0);
            acc[O1 + c] = MFMA16(ah[1], bl, acc[O1 + c], 0, 0, 0);
            acc[O1 + c] = MFMA16(al[1], bh, acc[O1 + c], 0, 0, 0);
        }
        if (c <= R2) {
            acc[O2 + c] = MFMA16(ah[2], bh, acc[O2 + c], 0, 0, 0);
            acc[O2 + c] = MFMA16(ah[2], bl, acc[O2 + c], 0, 0, 0);
            acc[O2 + c] = MFMA16(al[2], bh, acc[O2 + c], 0, 0, 0);
        }
        {
            acc[O3 + c] = MFMA16(ah[3], bh, acc[O3 + c], 0, 0, 0);
            acc[O3 + c] = MFMA16(ah[3], bl, acc[O3 + c], 0, 0, 0);
            acc[O3 + c] = MFMA16(al[3], bh, acc[O3 + c], 0, 0, 0);
        }
    }
}

template<int W>
__device__ __forceinline__ void cov_out(const f32x4* acc, float* Sc, int m, int kg) {
    constexpr int R[4] = {W, 7 - W, 8 + W, 15 - W};
    constexpr int O[4] = {0, W + 1, 9, 18 + W};
#pragma unroll
    for (int rr = 0; rr < 4; ++rr) {
        int i0 = R[rr] * 16 + kg * 4;
#pragma unroll
        for (int c = 0; c < 16; ++c) {
            if (c <= R[rr]) {
                int j = c * 16 + m;
#pragma unroll
                for (int q = 0; q < 4; ++q)
                    atomicAdd(&Sc[(i0 + q) * 256 + j], acc[O[rr] + c][q]);
            }
        }
    }
}

__global__ __launch_bounds__(256, 1) void k_cov(const float* __restrict__ x,
                                                float* __restrict__ S8,
                                                float* __restrict__ sums) {
    __shared__ unsigned lh[256 * 20];
    __shared__ unsigned ll_[256 * 20];
    int tid = threadIdx.x, wave = tid >> 6, lane = tid & 63;
    int m = lane & 15, kg = lane >> 4;
    const float* xc = x + (size_t)blockIdx.x * 896 * 256 + tid;
    f32x4 acc[34];
#pragma unroll
    for (int t = 0; t < 34; ++t) acc[t] = 0.f;
    float colsum = 0.f;

    for (int ch = 0; ch < 28; ++ch) {
        __syncthreads();
        const float* xr = xc + ch * 32 * 256;
#pragma unroll
        for (int rp = 0; rp < 16; ++rp) {
            float v0 = xr[(2 * rp) * 256];
            float v1 = xr[(2 * rp + 1) * 256];
            colsum += v0 + v1;
            unsigned h, l;
            split2(v0, v1, h, l);
            lh[tid * 20 + rp] = h;
            ll_[tid * 20 + rp] = l;
        }
        __syncthreads();
        if      (wave == 0) cov_step<0>(acc, lh, ll_, m, kg);
        else if (wave == 1) cov_step<1>(acc, lh, ll_, m, kg);
        else if (wave == 2) cov_step<2>(acc, lh, ll_, m, kg);
        else                cov_step<3>(acc, lh, ll_, m, kg);
    }
    atomicAdd(&sums[tid], colsum);
    float* Sc = S8 + (size_t)(blockIdx.x & 7) * 65536;
    if      (wave == 0) cov_out<0>(acc, Sc, m, kg);
    else if (wave == 1) cov_out<1>(acc, Sc, m, kg);
    else if (wave == 2) cov_out<2>(acc, Sc, m, kg);
    else                cov_out<3>(acc, Sc, m, kg);
}

// ---------------- K3a: init triangle from S8 partials ----------------
__global__ __launch_bounds__(256) void k_init(const float* __restrict__ S8,
                                              const float* __restrict__ sums,
                                              float* __restrict__ Lg) {
    int u = blockIdx.x * 256 + threadIdx.x;   // 0..16383
    int i = u >> 6, j0 = (u & 63) << 2;
    if (j0 > i) return;
    const float scale = (1.f - EPSV) / ((float)NROWS - 1.f);
    f32x4 s4 = 0.f;
#pragma unroll
    for (int p = 0; p < 8; ++p)
        s4 += *(const f32x4*)&S8[p * 65536 + i * C + j0];
    float mi = sums[i] * (1.f / (float)NROWS);
    f32x4 mj = *(const f32x4*)&sums[j0];
    int base = PAD(i);
#pragma unroll
    for (int e = 0; e < 4; ++e) {
        int j = j0 + e;
        if (j <= i) {
            float v = (s4[e] - mi * mj[e]) * scale;
            if (j == i) v += EPSV;
            Lg[base + j] = v;
        }
    }
}

// ---------------- K3b: per-panel diag factor + inverse + panel solve (1 block) ----------------
__global__ __launch_bounds__(512) void k_panel(float* __restrict__ Lg, int kb) {
    __shared__ __align__(16) float DS[32 * 36];   // Dinv square, zero-filled upper
    int tid = threadIdx.x;
    int lane = tid & 63;
    int k0 = kb * 32;

    if (tid < 64) {
        int col = lane & 31;
        float a[32];
#pragma unroll
        for (int i = 0; i < 32; ++i) {
            int ii = (i >= col) ? i : col;
            int jj = (i >= col) ? col : i;
            a[i] = Lg[PAD(k0 + ii) + k0 + jj];
        }
        float drec = 0.f;
#pragma unroll
        for (int k = 0; k < 32; ++k) {
            float akk = bcastf(a[k], k);
            float rinv = rsqrtf(akk);
            float myl = a[k] * rinv;
            bool up = (col > k);
#pragma unroll
            for (int i = k + 1; i < 32; ++i) {
                float lik = bcastf(a[i], k) * rinv;
                if (up) a[i] -= lik * myl;
                if (col == k) a[i] = lik;
            }
            if (col == k) { a[k] = akk * rinv; drec = rinv; }
        }
        float xv[32];
#pragma unroll
        for (int i = 0; i < 32; ++i) xv[i] = (col == i) ? 1.f : 0.f;
#pragma unroll
        for (int i = 0; i < 32; ++i) {
            float di = bcastf(drec, i);
            float xi = xv[i] * di;
            xv[i] = xi;
#pragma unroll
            for (int j = i + 1; j < 32; ++j) {
                float lji = bcastf(a[j], i);
                xv[j] -= lji * xi;
            }
        }
        if (lane < 32) {
#pragma unroll
            for (int i = 0; i < 32; ++i) {
                DS[i * 36 + col] = xv[i];
                if (i >= col) Lg[PAD(k0 + i) + k0 + col] = xv[i];
            }
        }
    }
    __syncthreads();

    int m = 224 - k0;
    int r = tid >> 1, g = tid & 1;
    if (r < m) {
        int abase = PAD(k0 + 32 + r) + k0;
        float4 av[8];
#pragma unroll
        for (int q = 0; q < 8; ++q) av[q] = *(const float4*)&Lg[abase + q * 4];
#pragma unroll
        for (int tgrp = 0; tgrp < 4; ++tgrp) {
            int cbase = g * 16 + tgrp * 4;
            float rv[4];
#pragma unroll
            for (int cc = 0; cc < 4; ++cc) {
                const float* drow = &DS[(cbase + cc) * 36];
                float s = 0.f;
#pragma unroll
                for (int q = 0; q < 8; ++q) {
                    float4 d4 = *(const float4*)&drow[q * 4];
                    s += av[q].x*d4.x + av[q].y*d4.y + av[q].z*d4.z + av[q].w*d4.w;
                }
                rv[cc] = s;
            }
            float4 res; res.x = rv[0]; res.y = rv[1]; res.z = rv[2]; res.w = rv[3];
            *(float4*)&Lg[abase + cbase] = res;
        }
    }
}

// ---------------- K3c: trailing update, one 32x32 block-pair per workgroup ----------------
__global__ __launch_bounds__(256) void k_trail(float* __restrict__ Lg, int kb) {
    __shared__ __align__(16) float As[32][36];
    __shared__ __align__(16) float Bs[32][36];
    int tid = threadIdx.x;
    int p = blockIdx.x;
    int a2 = 0;
    while (TRI(a2 + 1) <= p) ++a2;
    int b2 = p - TRI(a2);
    int ib2 = kb + 1 + a2, jb2 = kb + 1 + b2;
    int k0 = kb * 32;

    {
        int r = tid >> 3, cq = (tid & 7) * 4;
        *(float4*)&As[r][cq] = *(const float4*)&Lg[PAD(ib2 * 32 + r) + k0 + cq];
        *(float4*)&Bs[r][cq] = *(const float4*)&Lg[PAD(jb2 * 32 + r) + k0 + cq];
    }
    __syncthreads();

    int r2 = (tid >> 4) * 2, c2 = (tid & 15) * 2;
    float t00 = 0, t01 = 0, t10 = 0, t11 = 0;
#pragma unroll 8
    for (int q = 0; q < 32; ++q) {
        float a0 = As[r2][q], a1 = As[r2 + 1][q];
        float b0 = Bs[c2][q], b1 = Bs[c2 + 1][q];
        t00 += a0 * b0; t01 += a0 * b1;
        t10 += a1 * b0; t11 += a1 * b1;
    }
    int gi = ib2 * 32 + r2, gj = jb2 * 32 + c2;
    if (ib2 != jb2) {
        float* p0 = &Lg[PAD(gi) + gj];
        float* p1 = &Lg[PAD(gi + 1) + gj];
        p0[0] -= t00; p0[1] -= t01;
        p1[0] -= t10; p1[1] -= t11;
    } else {
        if (c2     <= r2    ) Lg[PAD(gi) + gj]         -= t00;
        if (c2 + 1 <= r2    ) Lg[PAD(gi) + gj + 1]     -= t01;
        if (c2     <= r2 + 1) Lg[PAD(gi + 1) + gj]     -= t10;
        if (c2 + 1 <= r2 + 1) Lg[PAD(gi + 1) + gj + 1] -= t11;
    }
}

// ---------------- K3d: blocked inverse, one block per W column-block (+ bf16 split epilogue) ----------------
__global__ __launch_bounds__(256) void k_inv(const float* __restrict__ Lg,
                                             const float* __restrict__ sums,
                                             const float* __restrict__ gamma,
                                             unsigned short* __restrict__ Wghi,
                                             unsigned short* __restrict__ Wglo,
                                             float* __restrict__ biasacc) {
    __shared__ __align__(16) float Wcol[256][36];
    __shared__ __align__(16) float Ls[32][36];
    __shared__ __align__(16) float Tst[32][36];
    int jbb = blockIdx.x;      // 0..7
    int tid = threadIdx.x;
    int j0 = jbb * 32;

    {
        int r = tid >> 3, cq = (tid & 7) * 4;
        const float* row = &Lg[PAD(j0 + r) + j0];
        float4 v;
        v.x = (cq     <= r) ? row[cq]     : 0.f;
        v.y = (cq + 1 <= r) ? row[cq + 1] : 0.f;
        v.z = (cq + 2 <= r) ? row[cq + 2] : 0.f;
        v.w = (cq + 3 <= r) ? row[cq + 3] : 0.f;
        *(float4*)&Wcol[j0 + r][cq] = v;
    }
    __syncthreads();

    int r2 = (tid >> 4) * 2, c2 = (tid & 15) * 2;
    for (int ib = jbb + 1; ib < 8; ++ib) {
        int i0 = ib * 32;
        float t00 = 0, t01 = 0, t10 = 0, t11 = 0;
        for (int kb = jbb; kb < ib; ++kb) {
            __syncthreads();
            {
                int r = tid >> 3, cq = (tid & 7) * 4;
                *(float4*)&Ls[r][cq] = *(const float4*)&Lg[PAD(i0 + r) + kb * 32 + cq];
            }
            __syncthreads();
            int kw = kb * 32;
#pragma unroll 8
            for (int q = 0; q < 32; ++q) {
                float l0 = Ls[r2][q], l1 = Ls[r2 + 1][q];
                float w0 = Wcol[kw + q][c2], w1 = Wcol[kw + q][c2 + 1];
                t00 += l0 * w0; t01 += l0 * w1;
                t10 += l1 * w0; t11 += l1 * w1;
            }
        }
        __syncthreads();
        Tst[r2][c2] = t00;     Tst[r2][c2 + 1] = t01;
        Tst[r2 + 1][c2] = t10; Tst[r2 + 1][c2 + 1] = t11;
        {
            int r = tid >> 3, cq = (tid & 7) * 4;
            const float* row = &Lg[PAD(i0 + r) + i0];
            float4 v;
            v.x = (cq     <= r) ? row[cq]     : 0.f;
            v.y = (cq + 1 <= r) ? row[cq + 1] : 0.f;
            v.z = (cq + 2 <= r) ? row[cq + 2] : 0.f;
            v.w = (cq + 3 <= r) ? row[cq + 3] : 0.f;
            *(float4*)&Ls[r][cq] = v;
        }
        __syncthreads();
        float w00 = 0, w01 = 0, w10 = 0, w11 = 0;
#pragma unroll 8
        for (int q = 0; q < 32; ++q) {
            float d0 = Ls[r2][q], d1 = Ls[r2 + 1][q];
            float tq0 = Tst[q][c2], tq1 = Tst[q][c2 + 1];
            w00 += d0 * tq0; w01 += d0 * tq1;
            w10 += d1 * tq0; w11 += d1 * tq1;
        }
        Wcol[i0 + r2][c2] = -w00;     Wcol[i0 + r2][c2 + 1] = -w01;
        Wcol[i0 + r2 + 1][c2] = -w10; Wcol[i0 + r2 + 1][c2 + 1] = -w11;
    }
    __syncthreads();

    {
        int r = tid;
        if (r >= j0) {
            float s = 0.f;
#pragma unroll 8
            for (int c = 0; c < 32; ++c)
                s += Wcol[r][c] * sums[j0 + c];
            atomicAdd(&biasacc[r], s * (1.f / (float)NROWS));
        }
    }
    for (int u = tid; u < 2048; u += 256) {
        int r = u >> 3, cq = (u & 7) * 4;
        float w0 = 0.f, w1 = 0.f, w2 = 0.f, w3 = 0.f;
        if (r >= j0) {
            float g = gamma[r];
            w0 = Wcol[r][cq] * g;     w1 = Wcol[r][cq + 1] * g;
            w2 = Wcol[r][cq + 2] * g; w3 = Wcol[r][cq + 3] * g;
        }
        unsigned h01, l01, h23, l23;
        split2(w0, w1, h01, l01);
        split2(w2, w3, h23, l23);
        unsigned idx = (unsigned)(r * 256 + j0 + cq) >> 1;
        ((unsigned*)Wghi)[idx]     = h01;
        ((unsigned*)Wghi)[idx + 1] = h23;
        ((unsigned*)Wglo)[idx]     = l01;
        ((unsigned*)Wglo)[idx + 1] = l23;
    }
}

// ---------------- K4: out = x * Wg^T + bias via bf16-split MFMA, LDS-staged A ----------------
// 128 rows/block, K in two 128-wide phases; x staged coalesced -> split bf16 hi/lo in LDS.
#define ASTRIDE 136   // ushort elems per LDS row (272B = 17*16B, 2-way bank alias only)
__global__ __launch_bounds__(256) void k_apply(const float* __restrict__ x,
                                               const unsigned short* __restrict__ Wghi,
                                               const unsigned short* __restrict__ Wglo,
                                               const float* __restrict__ beta,
                                               const float* __restrict__ gamma,
                                               const float* __restrict__ biasacc,
                                               float* __restrict__ out) {
    __shared__ unsigned short Ah[128 * ASTRIDE];   // 34 KB
    __shared__ unsigned short Al[128 * ASTRIDE];   // 34 KB
    int tid = threadIdx.x, wave = tid >> 6, lane = tid & 63;
    int m = lane & 15, kg = lane >> 4;
    size_t rblk = (size_t)blockIdx.x * 128;
    size_t rbase = rblk + wave * 32;

    f32x4 acc[32];
#pragma unroll
    for (int t = 0; t < 32; ++t) acc[t] = 0.f;

#pragma unroll
    for (int ph = 0; ph < 2; ++ph) {
        __syncthreads();
        // stage 128 rows x 128 cols of x, coalesced; split to bf16 hi/lo
#pragma unroll
        for (int it = 0; it < 16; ++it) {
            int f = it * 256 + tid;          // 0..4095 float4-groups
            int row = f >> 5;                // 0..127
            int c4 = f & 31;                 // float4-group within 128-col phase
            f32x4 v = *(const f32x4*)&x[(rblk + row) * 256 + ph * 128 + c4 * 4];
            u16x4 h, l;
#pragma unroll
            for (int e = 0; e < 4; ++e) {
                unsigned b = __float_as_uint(v[e]);
                h[e] = (unsigned short)(b >> 16);
                float lf = v[e] - __uint_as_float(b & 0xFFFF0000u);
                l[e] = (unsigned short)(__float_as_uint(lf) >> 16);
            }
            *(u16x4*)&Ah[row * ASTRIDE + c4 * 4] = h;
            *(u16x4*)&Al[row * ASTRIDE + c4 * 4] = l;
        }
        __syncthreads();

#pragma unroll
        for (int kc = 0; kc < 4; ++kc) {
            int kl = kc * 32 + kg * 8;
            int c0 = ph * 128 + kl;
            bf16x8 ah0 = *(const bf16x8*)&Ah[(wave * 32 + m) * ASTRIDE + kl];
            bf16x8 al0 = *(const bf16x8*)&Al[(wave * 32 + m) * ASTRIDE + kl];
            bf16x8 ah1 = *(const bf16x8*)&Ah[(wave * 32 + 16 + m) * ASTRIDE + kl];
            bf16x8 al1 = *(const bf16x8*)&Al[(wave * 32 + 16 + m) * ASTRIDE + kl];
#pragma unroll
            for (int jt = 0; jt < 16; ++jt) {
                int wo = (jt * 16 + m) * 256 + c0;
                bf16x8 bh = *(const bf16x8*)&Wghi[wo];
                bf16x8 bl = *(const bf16x8*)&Wglo[wo];
                acc[jt] = MFMA16(ah0, bh, acc[jt], 0, 0, 0);
                acc[jt] = MFMA16(ah0, bl, acc[jt], 0, 0, 0);
                acc[jt] = MFMA16(al0, bh, acc[jt], 0, 0, 0);
                acc[16 + jt] = MFMA16(ah1, bh, acc[16 + jt], 0, 0, 0);
                acc[16 + jt] = MFMA16(ah1, bl, acc[16 + jt], 0, 0, 0);
                acc[16 + jt] = MFMA16(al1, bh, acc[16 + jt], 0, 0, 0);
            }
        }
    }

#pragma unroll
    for (int jt = 0; jt < 16; ++jt) {
        int j = jt * 16 + m;
        float bb = beta[j] - gamma[j] * biasacc[j];
#pragma unroll
        for (int q = 0; q < 4; ++q) {
            out[(rbase + kg * 4 + q) * 256 + j]      = acc[jt][q] + bb;
            out[(rbase + 16 + kg * 4 + q) * 256 + j] = acc[16 + jt][q] + bb;
        }
    }
}

extern "C" void kernel_launch(void* const* d_in, const int* in_sizes, int n_in,
                              void* d_out, int out_size, void* d_ws, size_t ws_size,
                              hipStream_t stream) {
    const float* x     = (const float*)d_in[0];
    const float* gamma = (const float*)d_in[1];
    const float* beta  = (const float*)d_in[2];
    float* out  = (float*)d_out;
    float* ws   = (float*)d_ws;
    float* sums     = ws;                 // 256
    float* biasacc  = ws + 256;           // 256
    float* S8       = ws + 512;           // 8*65536
    float* Lg       = ws + 524800;        // 33280
    unsigned short* Wghi = (unsigned short*)(ws + 558080);   // 65536 bf16
    unsigned short* Wglo = (unsigned short*)(ws + 590848);   // 65536 bf16

    hipMemsetAsync(ws, 0, 524800 * sizeof(float), stream);
    hipLaunchKernelGGL(k_cov, dim3(224), dim3(256), 0, stream, x, S8, sums);
    hipLaunchKernelGGL(k_init, dim3(64), dim3(256), 0, stream, S8, sums, Lg);
    for (int kb = 0; kb < 8; ++kb) {
        hipLaunchKernelGGL(k_panel, dim3(1), dim3(512), 0, stream, Lg, kb);
        int np = TRI(7 - kb);
        if (np > 0)
            hipLaunchKernelGGL(k_trail, dim3(np), dim3(256), 0, stream, Lg, kb);
    }
    hipLaunchKernelGGL(k_inv, dim3(8), dim3(256), 0, stream, Lg, sums, gamma, Wghi, Wglo, biasacc);
    hipLaunchKernelGGL(k_apply, dim3(1568), dim3(256), 0, stream, x, Wghi, Wglo, beta, gamma, biasacc, out);
}

// Round 11
// 763.852 us; speedup vs baseline: 1.2097x; 1.2097x over previous
//
#include <hip/hip_runtime.h>
#include <hip/hip_bf16.h>
#include <math.h>

#define C 256
#define NROWS (64*56*56)   // 200704
#define EPSV 0.001f
#define TRI(i) (((i)*((i)+1))>>1)

typedef __attribute__((ext_vector_type(8))) short bf16x8;
typedef __attribute__((ext_vector_type(4))) float f32x4;
typedef __attribute__((ext_vector_type(4))) unsigned short u16x4;
#define MFMA16 __builtin_amdgcn_mfma_f32_16x16x32_bf16

// padded packed-lower-triangle layout: row i starts at PAD(i), rows rounded to 4 floats
__device__ __forceinline__ int PAD(int i) {
    int a = i >> 2, b = i & 3;
    return ((a + 1) * (2 * a + b)) << 2;
}

__device__ __forceinline__ float bcastf(float v, int l) {
    return __int_as_float(__builtin_amdgcn_readlane(__float_as_int(v), l));
}

__device__ __forceinline__ void split2(float v0, float v1, unsigned& hi, unsigned& lo) {
    unsigned b0 = __float_as_uint(v0), b1 = __float_as_uint(v1);
    hi = (b0 >> 16) | (b1 & 0xFFFF0000u);
    float l0 = v0 - __uint_as_float(b0 & 0xFFFF0000u);
    float l1 = v1 - __uint_as_float(b1 & 0xFFFF0000u);
    lo = (__float_as_uint(l0) >> 16) | (__float_as_uint(l1) & 0xFFFF0000u);
}

// ws layout (floats):
//  [0,256)          : channel sums
//  [256,512)        : biasacc
//  [512,524800)     : S8 = 8 copies of S partials (8*65536)
//  [524800,558080)  : Lg  = factored triangle
//  [558080,590848)  : Wphi (packed fragment-major bf16, 65536 ushort)
//  [590848,623616)  : Wplo

// ---------------- K2: S = X^T X via bf16-split MFMA + fused channel sums ----------------
template<int W>
__device__ __forceinline__ void cov_step(f32x4* acc, const unsigned* lh, const unsigned* ll,
                                         int m, int kg) {
    constexpr int R0 = W, R1 = 7 - W, R2 = 8 + W, R3 = 15 - W;
    constexpr int O0 = 0, O1 = W + 1, O2 = 9, O3 = 18 + W;
    bf16x8 ah[4], al[4];
    {
        int o0 = (R0 * 16 + m) * 20 + kg * 4;
        int o1 = (R1 * 16 + m) * 20 + kg * 4;
        int o2 = (R2 * 16 + m) * 20 + kg * 4;
        int o3 = (R3 * 16 + m) * 20 + kg * 4;
        ah[0] = *(const bf16x8*)&lh[o0]; al[0] = *(const bf16x8*)&ll[o0];
        ah[1] = *(const bf16x8*)&lh[o1]; al[1] = *(const bf16x8*)&ll[o1];
        ah[2] = *(const bf16x8*)&lh[o2]; al[2] = *(const bf16x8*)&ll[o2];
        ah[3] = *(const bf16x8*)&lh[o3]; al[3] = *(const bf16x8*)&ll[o3];
    }
#pragma unroll
    for (int c = 0; c <= R3; ++c) {
        int o = (c * 16 + m) * 20 + kg * 4;
        bf16x8 bh = *(const bf16x8*)&lh[o];
        bf16x8 bl = *(const bf16x8*)&ll[o];
        if (c <= R0) {
            acc[O0 + c] = MFMA16(ah[0], bh, acc[O0 + c], 0, 0, 0);
            acc[O0 + c] = MFMA16(ah[0], bl, acc[O0 + c], 0, 0, 0);
            acc[O0 + c] = MFMA16(al[0], bh, acc[O0 + c], 0, 0, 0);
        }
        if (c <= R1) {
            acc[O1 + c] = MFMA16(ah[1], bh, acc[O1 + c], 0, 0, 0);
            acc[O1 + c] = MFMA16(ah[1], bl, acc[O1 + c], 0, 0, 0);
            acc[O1 + c] = MFMA16(al[1], bh, acc[O1 + c], 0, 0, 0);
        }
        if (c <= R2) {
            acc[O2 + c] = MFMA16(ah[2], bh, acc[O2 + c], 0, 0, 0);
            acc[O2 + c] = MFMA16(ah[2], bl, acc[O2 + c], 0, 0, 0);
            acc[O2 + c] = MFMA16(al[2], bh, acc[O2 + c], 0, 0, 0);
        }
        {
            acc[O3 + c] = MFMA16(ah[3], bh, acc[O3 + c], 0, 0, 0);
            acc[O3 + c] = MFMA16(ah[3], bl, acc[O3 + c], 0, 0, 0);
            acc[O3 + c] = MFMA16(al[3], bh, acc[O3 + c], 0, 0, 0);
        }
    }
}

template<int W>
__device__ __forceinline__ void cov_out(const f32x4* acc, float* Sc, int m, int kg) {
    constexpr int R[4] = {W, 7 - W, 8 + W, 15 - W};
    constexpr int O[4] = {0, W + 1, 9, 18 + W};
#pragma unroll
    for (int rr = 0; rr < 4; ++rr) {
        int i0 = R[rr] * 16 + kg * 4;
#pragma unroll
        for (int c = 0; c < 16; ++c) {
            if (c <= R[rr]) {
                int j = c * 16 + m;
#pragma unroll
                for (int q = 0; q < 4; ++q)
                    atomicAdd(&Sc[(i0 + q) * 256 + j], acc[O[rr] + c][q]);
            }
        }
    }
}

__global__ __launch_bounds__(256, 1) void k_cov(const float* __restrict__ x,
                                                float* __restrict__ S8,
                                                float* __restrict__ sums) {
    __shared__ unsigned lh[256 * 20];
    __shared__ unsigned ll_[256 * 20];
    int tid = threadIdx.x, wave = tid >> 6, lane = tid & 63;
    int m = lane & 15, kg = lane >> 4;
    const float* xc = x + (size_t)blockIdx.x * 896 * 256 + tid;
    f32x4 acc[34];
#pragma unroll
    for (int t = 0; t < 34; ++t) acc[t] = 0.f;
    float colsum = 0.f;

    for (int ch = 0; ch < 28; ++ch) {
        __syncthreads();
        const float* xr = xc + ch * 32 * 256;
#pragma unroll
        for (int rp = 0; rp < 16; ++rp) {
            float v0 = xr[(2 * rp) * 256];
            float v1 = xr[(2 * rp + 1) * 256];
            colsum += v0 + v1;
            unsigned h, l;
            split2(v0, v1, h, l);
            lh[tid * 20 + rp] = h;
            ll_[tid * 20 + rp] = l;
        }
        __syncthreads();
        if      (wave == 0) cov_step<0>(acc, lh, ll_, m, kg);
        else if (wave == 1) cov_step<1>(acc, lh, ll_, m, kg);
        else if (wave == 2) cov_step<2>(acc, lh, ll_, m, kg);
        else                cov_step<3>(acc, lh, ll_, m, kg);
    }
    atomicAdd(&sums[tid], colsum);
    float* Sc = S8 + (size_t)(blockIdx.x & 7) * 65536;
    if      (wave == 0) cov_out<0>(acc, Sc, m, kg);
    else if (wave == 1) cov_out<1>(acc, Sc, m, kg);
    else if (wave == 2) cov_out<2>(acc, Sc, m, kg);
    else                cov_out<3>(acc, Sc, m, kg);
}

// ---------------- K3a: init triangle from S8 partials ----------------
__global__ __launch_bounds__(256) void k_init(const float* __restrict__ S8,
                                              const float* __restrict__ sums,
                                              float* __restrict__ Lg) {
    int u = blockIdx.x * 256 + threadIdx.x;   // 0..16383
    int i = u >> 6, j0 = (u & 63) << 2;
    if (j0 > i) return;
    const float scale = (1.f - EPSV) / ((float)NROWS - 1.f);
    f32x4 s4 = 0.f;
#pragma unroll
    for (int p = 0; p < 8; ++p)
        s4 += *(const f32x4*)&S8[p * 65536 + i * C + j0];
    float mi = sums[i] * (1.f / (float)NROWS);
    f32x4 mj = *(const f32x4*)&sums[j0];
    int base = PAD(i);
#pragma unroll
    for (int e = 0; e < 4; ++e) {
        int j = j0 + e;
        if (j <= i) {
            float v = (s4[e] - mi * mj[e]) * scale;
            if (j == i) v += EPSV;
            Lg[base + j] = v;
        }
    }
}

// ---------------- K3b: per-panel diag factor + inverse + panel solve (1 block) ----------------
__global__ __launch_bounds__(512) void k_panel(float* __restrict__ Lg, int kb) {
    __shared__ __align__(16) float DS[32 * 36];
    int tid = threadIdx.x;
    int lane = tid & 63;
    int k0 = kb * 32;

    if (tid < 64) {
        int col = lane & 31;
        float a[32];
#pragma unroll
        for (int i = 0; i < 32; ++i) {
            int ii = (i >= col) ? i : col;
            int jj = (i >= col) ? col : i;
            a[i] = Lg[PAD(k0 + ii) + k0 + jj];
        }
        float drec = 0.f;
#pragma unroll
        for (int k = 0; k < 32; ++k) {
            float akk = bcastf(a[k], k);
            float rinv = rsqrtf(akk);
            float myl = a[k] * rinv;
            bool up = (col > k);
#pragma unroll
            for (int i = k + 1; i < 32; ++i) {
                float lik = bcastf(a[i], k) * rinv;
                if (up) a[i] -= lik * myl;
                if (col == k) a[i] = lik;
            }
            if (col == k) { a[k] = akk * rinv; drec = rinv; }
        }
        float xv[32];
#pragma unroll
        for (int i = 0; i < 32; ++i) xv[i] = (col == i) ? 1.f : 0.f;
#pragma unroll
        for (int i = 0; i < 32; ++i) {
            float di = bcastf(drec, i);
            float xi = xv[i] * di;
            xv[i] = xi;
#pragma unroll
            for (int j = i + 1; j < 32; ++j) {
                float lji = bcastf(a[j], i);
                xv[j] -= lji * xi;
            }
        }
        if (lane < 32) {
#pragma unroll
            for (int i = 0; i < 32; ++i) {
                DS[i * 36 + col] = xv[i];
                if (i >= col) Lg[PAD(k0 + i) + k0 + col] = xv[i];
            }
        }
    }
    __syncthreads();

    int m = 224 - k0;
    int r = tid >> 1, g = tid & 1;
    if (r < m) {
        int abase = PAD(k0 + 32 + r) + k0;
        float4 av[8];
#pragma unroll
        for (int q = 0; q < 8; ++q) av[q] = *(const float4*)&Lg[abase + q * 4];
#pragma unroll
        for (int tgrp = 0; tgrp < 4; ++tgrp) {
            int cbase = g * 16 + tgrp * 4;
            float rv[4];
#pragma unroll
            for (int cc = 0; cc < 4; ++cc) {
                const float* drow = &DS[(cbase + cc) * 36];
                float s = 0.f;
#pragma unroll
                for (int q = 0; q < 8; ++q) {
                    float4 d4 = *(const float4*)&drow[q * 4];
                    s += av[q].x*d4.x + av[q].y*d4.y + av[q].z*d4.z + av[q].w*d4.w;
                }
                rv[cc] = s;
            }
            float4 res; res.x = rv[0]; res.y = rv[1]; res.z = rv[2]; res.w = rv[3];
            *(float4*)&Lg[abase + cbase] = res;
        }
    }
}

// ---------------- K3c: trailing update, one 32x32 block-pair per workgroup ----------------
__global__ __launch_bounds__(256) void k_trail(float* __restrict__ Lg, int kb) {
    __shared__ __align__(16) float As[32][36];
    __shared__ __align__(16) float Bs[32][36];
    int tid = threadIdx.x;
    int p = blockIdx.x;
    int a2 = 0;
    while (TRI(a2 + 1) <= p) ++a2;
    int b2 = p - TRI(a2);
    int ib2 = kb + 1 + a2, jb2 = kb + 1 + b2;
    int k0 = kb * 32;

    {
        int r = tid >> 3, cq = (tid & 7) * 4;
        *(float4*)&As[r][cq] = *(const float4*)&Lg[PAD(ib2 * 32 + r) + k0 + cq];
        *(float4*)&Bs[r][cq] = *(const float4*)&Lg[PAD(jb2 * 32 + r) + k0 + cq];
    }
    __syncthreads();

    int r2 = (tid >> 4) * 2, c2 = (tid & 15) * 2;
    float t00 = 0, t01 = 0, t10 = 0, t11 = 0;
#pragma unroll 8
    for (int q = 0; q < 32; ++q) {
        float a0 = As[r2][q], a1 = As[r2 + 1][q];
        float b0 = Bs[c2][q], b1 = Bs[c2 + 1][q];
        t00 += a0 * b0; t01 += a0 * b1;
        t10 += a1 * b0; t11 += a1 * b1;
    }
    int gi = ib2 * 32 + r2, gj = jb2 * 32 + c2;
    if (ib2 != jb2) {
        float* p0 = &Lg[PAD(gi) + gj];
        float* p1 = &Lg[PAD(gi + 1) + gj];
        p0[0] -= t00; p0[1] -= t01;
        p1[0] -= t10; p1[1] -= t11;
    } else {
        if (c2     <= r2    ) Lg[PAD(gi) + gj]         -= t00;
        if (c2 + 1 <= r2    ) Lg[PAD(gi) + gj + 1]     -= t01;
        if (c2     <= r2 + 1) Lg[PAD(gi + 1) + gj]     -= t10;
        if (c2 + 1 <= r2 + 1) Lg[PAD(gi + 1) + gj + 1] -= t11;
    }
}

// ---------------- K3d: blocked inverse + packed fragment-major bf16 epilogue ----------------
__global__ __launch_bounds__(256) void k_inv(const float* __restrict__ Lg,
                                             const float* __restrict__ sums,
                                             const float* __restrict__ gamma,
                                             unsigned short* __restrict__ Wphi,
                                             unsigned short* __restrict__ Wplo,
                                             float* __restrict__ biasacc) {
    __shared__ __align__(16) float Wcol[256][36];
    __shared__ __align__(16) float Ls[32][36];
    __shared__ __align__(16) float Tst[32][36];
    int jbb = blockIdx.x;      // 0..7 == kcg
    int tid = threadIdx.x;
    int j0 = jbb * 32;

    {
        int r = tid >> 3, cq = (tid & 7) * 4;
        const float* row = &Lg[PAD(j0 + r) + j0];
        float4 v;
        v.x = (cq     <= r) ? row[cq]     : 0.f;
        v.y = (cq + 1 <= r) ? row[cq + 1] : 0.f;
        v.z = (cq + 2 <= r) ? row[cq + 2] : 0.f;
        v.w = (cq + 3 <= r) ? row[cq + 3] : 0.f;
        *(float4*)&Wcol[j0 + r][cq] = v;
    }
    __syncthreads();

    int r2 = (tid >> 4) * 2, c2 = (tid & 15) * 2;
    for (int ib = jbb + 1; ib < 8; ++ib) {
        int i0 = ib * 32;
        float t00 = 0, t01 = 0, t10 = 0, t11 = 0;
        for (int kb = jbb; kb < ib; ++kb) {
            __syncthreads();
            {
                int r = tid >> 3, cq = (tid & 7) * 4;
                *(float4*)&Ls[r][cq] = *(const float4*)&Lg[PAD(i0 + r) + kb * 32 + cq];
            }
            __syncthreads();
            int kw = kb * 32;
#pragma unroll 8
            for (int q = 0; q < 32; ++q) {
                float l0 = Ls[r2][q], l1 = Ls[r2 + 1][q];
                float w0 = Wcol[kw + q][c2], w1 = Wcol[kw + q][c2 + 1];
                t00 += l0 * w0; t01 += l0 * w1;
                t10 += l1 * w0; t11 += l1 * w1;
            }
        }
        __syncthreads();
        Tst[r2][c2] = t00;     Tst[r2][c2 + 1] = t01;
        Tst[r2 + 1][c2] = t10; Tst[r2 + 1][c2 + 1] = t11;
        {
            int r = tid >> 3, cq = (tid & 7) * 4;
            const float* row = &Lg[PAD(i0 + r) + i0];
            float4 v;
            v.x = (cq     <= r) ? row[cq]     : 0.f;
            v.y = (cq + 1 <= r) ? row[cq + 1] : 0.f;
            v.z = (cq + 2 <= r) ? row[cq + 2] : 0.f;
            v.w = (cq + 3 <= r) ? row[cq + 3] : 0.f;
            *(float4*)&Ls[r][cq] = v;
        }
        __syncthreads();
        float w00 = 0, w01 = 0, w10 = 0, w11 = 0;
#pragma unroll 8
        for (int q = 0; q < 32; ++q) {
            float d0 = Ls[r2][q], d1 = Ls[r2 + 1][q];
            float tq0 = Tst[q][c2], tq1 = Tst[q][c2 + 1];
            w00 += d0 * tq0; w01 += d0 * tq1;
            w10 += d1 * tq0; w11 += d1 * tq1;
        }
        Wcol[i0 + r2][c2] = -w00;     Wcol[i0 + r2][c2 + 1] = -w01;
        Wcol[i0 + r2 + 1][c2] = -w10; Wcol[i0 + r2 + 1][c2 + 1] = -w11;
    }
    __syncthreads();

    {
        int r = tid;
        if (r >= j0) {
            float s = 0.f;
#pragma unroll 8
            for (int c = 0; c < 32; ++c)
                s += Wcol[r][c] * sums[j0 + c];
            atomicAdd(&biasacc[r], s * (1.f / (float)NROWS));
        }
    }
    // packed fragment-major epilogue: Wp[((jt*8 + jbb)*64 + l)*8 + j]
    //   = split(gamma[row] * W[row][j0 + (l>>4)*8 + j]),  row = jt*16 + (l&15)
    for (int pi = tid; pi < 1024; pi += 256) {
        int jt = pi >> 6, l = pi & 63;
        int row = jt * 16 + (l & 15);
        int cb = (l >> 4) * 8;
        float g = (row >= j0) ? gamma[row] : 0.f;
        u16x4 h0, h1, lo0, lo1;
#pragma unroll
        for (int j = 0; j < 8; ++j) {
            float v = (row >= j0) ? g * Wcol[row][cb + j] : 0.f;
            unsigned b = __float_as_uint(v);
            unsigned short hi = (unsigned short)(b >> 16);
            float lf = v - __uint_as_float(b & 0xFFFF0000u);
            unsigned short lo = (unsigned short)(__float_as_uint(lf) >> 16);
            if (j < 4) { h0[j] = hi; lo0[j] = lo; }
            else       { h1[j - 4] = hi; lo1[j - 4] = lo; }
        }
        size_t base = ((size_t)(jt * 8 + jbb) * 64 + l) * 8;
        *(u16x4*)&Wphi[base]     = h0;
        *(u16x4*)&Wphi[base + 4] = h1;
        *(u16x4*)&Wplo[base]     = lo0;
        *(u16x4*)&Wplo[base + 4] = lo1;
    }
}

// ---------------- K4: out = bf16(x) * Wg^T + bias, packed-contiguous B fragments ----------------
#define ASTR 264   // ushorts per LDS row (528B; 16B-aligned, stride ≡ 4 banks)
__global__ __launch_bounds__(256) void k_apply(const float* __restrict__ x,
                                               const unsigned short* __restrict__ Wphi,
                                               const unsigned short* __restrict__ Wplo,
                                               const float* __restrict__ beta,
                                               const float* __restrict__ gamma,
                                               const float* __restrict__ biasacc,
                                               float* __restrict__ out) {
    __shared__ unsigned short Ah[128 * ASTR];   // 66 KB
    int tid = threadIdx.x, wave = tid >> 6, lane = tid & 63;
    int m = lane & 15, kg = lane >> 4;
    size_t rblk = (size_t)blockIdx.x * 128;
    size_t rbase = rblk + wave * 32;

    // stage full 128x256 x-tile as RNE-rounded bf16, fully coalesced
#pragma unroll
    for (int it = 0; it < 32; ++it) {
        int f = it * 256 + tid;          // 0..8191 float4-groups
        int row = f >> 6, c4 = f & 63;
        f32x4 v = *(const f32x4*)&x[(rblk + row) * 256 + c4 * 4];
        u16x4 h;
#pragma unroll
        for (int e = 0; e < 4; ++e) {
            unsigned b = __float_as_uint(v[e]);
            b += 0x7FFFu + ((b >> 16) & 1u);   // round-to-nearest-even
            h[e] = (unsigned short)(b >> 16);
        }
        *(u16x4*)&Ah[row * ASTR + c4 * 4] = h;
    }
    __syncthreads();

    f32x4 acc[32];
#pragma unroll
    for (int t = 0; t < 32; ++t) acc[t] = 0.f;

    int arow0 = (wave * 32 + m) * ASTR + kg * 8;
    int arow1 = arow0 + 16 * ASTR;
#pragma unroll
    for (int kcg = 0; kcg < 8; ++kcg) {
        bf16x8 ah0 = *(const bf16x8*)&Ah[arow0 + kcg * 32];
        bf16x8 ah1 = *(const bf16x8*)&Ah[arow1 + kcg * 32];
#pragma unroll
        for (int jt = 0; jt < 16; ++jt) {
            size_t wo = ((size_t)(jt * 8 + kcg) * 64 + lane) * 8;  // contiguous 1KB/wave
            bf16x8 bh = *(const bf16x8*)&Wphi[wo];
            bf16x8 bl = *(const bf16x8*)&Wplo[wo];
            acc[jt]      = MFMA16(ah0, bh, acc[jt], 0, 0, 0);
            acc[jt]      = MFMA16(ah0, bl, acc[jt], 0, 0, 0);
            acc[16 + jt] = MFMA16(ah1, bh, acc[16 + jt], 0, 0, 0);
            acc[16 + jt] = MFMA16(ah1, bl, acc[16 + jt], 0, 0, 0);
        }
    }

#pragma unroll
    for (int jt = 0; jt < 16; ++jt) {
        int j = jt * 16 + m;
        float bb = beta[j] - gamma[j] * biasacc[j];
#pragma unroll
        for (int q = 0; q < 4; ++q) {
            out[(rbase + kg * 4 + q) * 256 + j]      = acc[jt][q] + bb;
            out[(rbase + 16 + kg * 4 + q) * 256 + j] = acc[16 + jt][q] + bb;
        }
    }
}

extern "C" void kernel_launch(void* const* d_in, const int* in_sizes, int n_in,
                              void* d_out, int out_size, void* d_ws, size_t ws_size,
                              hipStream_t stream) {
    const float* x     = (const float*)d_in[0];
    const float* gamma = (const float*)d_in[1];
    const float* beta  = (const float*)d_in[2];
    float* out  = (float*)d_out;
    float* ws   = (float*)d_ws;
    float* sums     = ws;                 // 256
    float* biasacc  = ws + 256;           // 256
    float* S8       = ws + 512;           // 8*65536
    float* Lg       = ws + 524800;        // 33280
    unsigned short* Wphi = (unsigned short*)(ws + 558080);   // 65536 bf16
    unsigned short* Wplo = (unsigned short*)(ws + 590848);   // 65536 bf16

    hipMemsetAsync(ws, 0, 524800 * sizeof(float), stream);
    hipLaunchKernelGGL(k_cov, dim3(224), dim3(256), 0, stream, x, S8, sums);
    hipLaunchKernelGGL(k_init, dim3(64), dim3(256), 0, stream, S8, sums, Lg);
    for (int kb = 0; kb < 8; ++kb) {
        hipLaunchKernelGGL(k_panel, dim3(1), dim3(512), 0, stream, Lg, kb);
        int np = TRI(7 - kb);
        if (np > 0)
            hipLaunchKernelGGL(k_trail, dim3(np), dim3(256), 0, stream, Lg, kb);
    }
    hipLaunchKernelGGL(k_inv, dim3(8), dim3(256), 0, stream, Lg, sums, gamma, Wphi, Wplo, biasacc);
    hipLaunchKernelGGL(k_apply, dim3(1568), dim3(256), 0, stream, x, Wphi, Wplo, beta, gamma, biasacc, out);
}

// Round 12
// 723.204 us; speedup vs baseline: 1.2777x; 1.0562x over previous
//
#include <hip/hip_runtime.h>
#include <hip/hip_bf16.h>
#include <math.h>

#define C 256
#define NROWS (64*56*56)   // 200704
#define EPSV 0.001f
#define TRI(i) (((i)*((i)+1))>>1)

typedef __attribute__((ext_vector_type(8))) short bf16x8;
typedef __attribute__((ext_vector_type(4))) float f32x4;
typedef __attribute__((ext_vector_type(4))) unsigned short u16x4;
#define MFMA16 __builtin_amdgcn_mfma_f32_16x16x32_bf16

// padded packed-lower-triangle layout: row i starts at PAD(i), rows rounded to 4 floats
__device__ __forceinline__ int PAD(int i) {
    int a = i >> 2, b = i & 3;
    return ((a + 1) * (2 * a + b)) << 2;
}

__device__ __forceinline__ float bcastf(float v, int l) {
    return __int_as_float(__builtin_amdgcn_readlane(__float_as_int(v), l));
}

__device__ __forceinline__ void split2(float v0, float v1, unsigned& hi, unsigned& lo) {
    unsigned b0 = __float_as_uint(v0), b1 = __float_as_uint(v1);
    hi = (b0 >> 16) | (b1 & 0xFFFF0000u);
    float l0 = v0 - __uint_as_float(b0 & 0xFFFF0000u);
    float l1 = v1 - __uint_as_float(b1 & 0xFFFF0000u);
    lo = (__float_as_uint(l0) >> 16) | (__float_as_uint(l1) & 0xFFFF0000u);
}

// ws layout (floats):
//  [0,256)          : channel sums
//  [256,512)        : biasacc
//  [512,524800)     : S8 = 8 copies of S partials (8*65536)
//  [524800,558080)  : Lg  = factored triangle
//  [558080,590848)  : Wphi (packed fragment-major bf16, 65536 ushort)
//  [590848,623616)  : Wplo

// ---------------- K2: S = X^T X via bf16-split MFMA + fused channel sums ----------------
template<int W>
__device__ __forceinline__ void cov_step(f32x4* acc, const unsigned* lh, const unsigned* ll,
                                         int m, int kg) {
    constexpr int R0 = W, R1 = 7 - W, R2 = 8 + W, R3 = 15 - W;
    constexpr int O0 = 0, O1 = W + 1, O2 = 9, O3 = 18 + W;
    bf16x8 ah[4], al[4];
    {
        int o0 = (R0 * 16 + m) * 20 + kg * 4;
        int o1 = (R1 * 16 + m) * 20 + kg * 4;
        int o2 = (R2 * 16 + m) * 20 + kg * 4;
        int o3 = (R3 * 16 + m) * 20 + kg * 4;
        ah[0] = *(const bf16x8*)&lh[o0]; al[0] = *(const bf16x8*)&ll[o0];
        ah[1] = *(const bf16x8*)&lh[o1]; al[1] = *(const bf16x8*)&ll[o1];
        ah[2] = *(const bf16x8*)&lh[o2]; al[2] = *(const bf16x8*)&ll[o2];
        ah[3] = *(const bf16x8*)&lh[o3]; al[3] = *(const bf16x8*)&ll[o3];
    }
#pragma unroll
    for (int c = 0; c <= R3; ++c) {
        int o = (c * 16 + m) * 20 + kg * 4;
        bf16x8 bh = *(const bf16x8*)&lh[o];
        bf16x8 bl = *(const bf16x8*)&ll[o];
        if (c <= R0) {
            acc[O0 + c] = MFMA16(ah[0], bh, acc[O0 + c], 0, 0, 0);
            acc[O0 + c] = MFMA16(ah[0], bl, acc[O0 + c], 0, 0, 0);
            acc[O0 + c] = MFMA16(al[0], bh, acc[O0 + c], 0, 0, 0);
        }
        if (c <= R1) {
            acc[O1 + c] = MFMA16(ah[1], bh, acc[O1 + c], 0, 0, 0);
            acc[O1 + c] = MFMA16(ah[1], bl, acc[O1 + c], 0, 0, 0);
            acc[O1 + c] = MFMA16(al[1], bh, acc[O1 + c], 0, 0, 0);
        }
        if (c <= R2) {
            acc[O2 + c] = MFMA16(ah[2], bh, acc[O2 + c], 0, 0, 0);
            acc[O2 + c] = MFMA16(ah[2], bl, acc[O2 + c], 0, 0, 0);
            acc[O2 + c] = MFMA16(al[2], bh, acc[O2 + c], 0, 0, 0);
        }
        {
            acc[O3 + c] = MFMA16(ah[3], bh, acc[O3 + c], 0, 0, 0);
            acc[O3 + c] = MFMA16(ah[3], bl, acc[O3 + c], 0, 0, 0);
            acc[O3 + c] = MFMA16(al[3], bh, acc[O3 + c], 0, 0, 0);
        }
    }
}

template<int W>
__device__ __forceinline__ void cov_out(const f32x4* acc, float* Sc, int m, int kg) {
    constexpr int R[4] = {W, 7 - W, 8 + W, 15 - W};
    constexpr int O[4] = {0, W + 1, 9, 18 + W};
#pragma unroll
    for (int rr = 0; rr < 4; ++rr) {
        int i0 = R[rr] * 16 + kg * 4;
#pragma unroll
        for (int c = 0; c < 16; ++c) {
            if (c <= R[rr]) {
                int j = c * 16 + m;
#pragma unroll
                for (int q = 0; q < 4; ++q)
                    atomicAdd(&Sc[(i0 + q) * 256 + j], acc[O[rr] + c][q]);
            }
        }
    }
}

// 448 blocks x 448 rows (14 staging iters) -> ~2 blocks/CU for latency hiding
__global__ __launch_bounds__(256, 1) void k_cov(const float* __restrict__ x,
                                                float* __restrict__ S8,
                                                float* __restrict__ sums) {
    __shared__ unsigned lh[256 * 20];
    __shared__ unsigned ll_[256 * 20];
    int tid = threadIdx.x, wave = tid >> 6, lane = tid & 63;
    int m = lane & 15, kg = lane >> 4;
    const float* xc = x + (size_t)blockIdx.x * 448 * 256 + tid;
    f32x4 acc[34];
#pragma unroll
    for (int t = 0; t < 34; ++t) acc[t] = 0.f;
    float colsum = 0.f;

    for (int ch = 0; ch < 14; ++ch) {
        __syncthreads();
        const float* xr = xc + ch * 32 * 256;
#pragma unroll
        for (int rp = 0; rp < 16; ++rp) {
            float v0 = xr[(2 * rp) * 256];
            float v1 = xr[(2 * rp + 1) * 256];
            colsum += v0 + v1;
            unsigned h, l;
            split2(v0, v1, h, l);
            lh[tid * 20 + rp] = h;
            ll_[tid * 20 + rp] = l;
        }
        __syncthreads();
        if      (wave == 0) cov_step<0>(acc, lh, ll_, m, kg);
        else if (wave == 1) cov_step<1>(acc, lh, ll_, m, kg);
        else if (wave == 2) cov_step<2>(acc, lh, ll_, m, kg);
        else                cov_step<3>(acc, lh, ll_, m, kg);
    }
    atomicAdd(&sums[tid], colsum);
    float* Sc = S8 + (size_t)(blockIdx.x & 7) * 65536;
    if      (wave == 0) cov_out<0>(acc, Sc, m, kg);
    else if (wave == 1) cov_out<1>(acc, Sc, m, kg);
    else if (wave == 2) cov_out<2>(acc, Sc, m, kg);
    else                cov_out<3>(acc, Sc, m, kg);
}

// ---------------- K3a: init triangle from S8 partials ----------------
__global__ __launch_bounds__(256) void k_init(const float* __restrict__ S8,
                                              const float* __restrict__ sums,
                                              float* __restrict__ Lg) {
    int u = blockIdx.x * 256 + threadIdx.x;   // 0..16383
    int i = u >> 6, j0 = (u & 63) << 2;
    if (j0 > i) return;
    const float scale = (1.f - EPSV) / ((float)NROWS - 1.f);
    f32x4 s4 = 0.f;
#pragma unroll
    for (int p = 0; p < 8; ++p)
        s4 += *(const f32x4*)&S8[p * 65536 + i * C + j0];
    float mi = sums[i] * (1.f / (float)NROWS);
    f32x4 mj = *(const f32x4*)&sums[j0];
    int base = PAD(i);
#pragma unroll
    for (int e = 0; e < 4; ++e) {
        int j = j0 + e;
        if (j <= i) {
            float v = (s4[e] - mi * mj[e]) * scale;
            if (j == i) v += EPSV;
            Lg[base + j] = v;
        }
    }
}

// ---------------- K3b: per-panel diag factor + inverse + panel solve (1 block) ----------------
__global__ __launch_bounds__(512) void k_panel(float* __restrict__ Lg, int kb) {
    __shared__ __align__(16) float DS[32 * 36];
    int tid = threadIdx.x;
    int lane = tid & 63;
    int k0 = kb * 32;

    if (tid < 64) {
        int col = lane & 31;
        float a[32];
#pragma unroll
        for (int i = 0; i < 32; ++i) {
            int ii = (i >= col) ? i : col;
            int jj = (i >= col) ? col : i;
            a[i] = Lg[PAD(k0 + ii) + k0 + jj];
        }
        float drec = 0.f;
#pragma unroll
        for (int k = 0; k < 32; ++k) {
            float akk = bcastf(a[k], k);
            float rinv = rsqrtf(akk);
            float myl = a[k] * rinv;
            bool up = (col > k);
#pragma unroll
            for (int i = k + 1; i < 32; ++i) {
                float lik = bcastf(a[i], k) * rinv;
                if (up) a[i] -= lik * myl;
                if (col == k) a[i] = lik;
            }
            if (col == k) { a[k] = akk * rinv; drec = rinv; }
        }
        float xv[32];
#pragma unroll
        for (int i = 0; i < 32; ++i) xv[i] = (col == i) ? 1.f : 0.f;
#pragma unroll
        for (int i = 0; i < 32; ++i) {
            float di = bcastf(drec, i);
            float xi = xv[i] * di;
            xv[i] = xi;
#pragma unroll
            for (int j = i + 1; j < 32; ++j) {
                float lji = bcastf(a[j], i);
                xv[j] -= lji * xi;
            }
        }
        if (lane < 32) {
#pragma unroll
            for (int i = 0; i < 32; ++i) {
                DS[i * 36 + col] = xv[i];
                if (i >= col) Lg[PAD(k0 + i) + k0 + col] = xv[i];
            }
        }
    }
    __syncthreads();

    int m = 224 - k0;
    int r = tid >> 1, g = tid & 1;
    if (r < m) {
        int abase = PAD(k0 + 32 + r) + k0;
        float4 av[8];
#pragma unroll
        for (int q = 0; q < 8; ++q) av[q] = *(const float4*)&Lg[abase + q * 4];
#pragma unroll
        for (int tgrp = 0; tgrp < 4; ++tgrp) {
            int cbase = g * 16 + tgrp * 4;
            float rv[4];
#pragma unroll
            for (int cc = 0; cc < 4; ++cc) {
                const float* drow = &DS[(cbase + cc) * 36];
                float s = 0.f;
#pragma unroll
                for (int q = 0; q < 8; ++q) {
                    float4 d4 = *(const float4*)&drow[q * 4];
                    s += av[q].x*d4.x + av[q].y*d4.y + av[q].z*d4.z + av[q].w*d4.w;
                }
                rv[cc] = s;
            }
            float4 res; res.x = rv[0]; res.y = rv[1]; res.z = rv[2]; res.w = rv[3];
            *(float4*)&Lg[abase + cbase] = res;
        }
    }
}

// ---------------- K3c: trailing update, one 32x32 block-pair per workgroup ----------------
__global__ __launch_bounds__(256) void k_trail(float* __restrict__ Lg, int kb) {
    __shared__ __align__(16) float As[32][36];
    __shared__ __align__(16) float Bs[32][36];
    int tid = threadIdx.x;
    int p = blockIdx.x;
    int a2 = 0;
    while (TRI(a2 + 1) <= p) ++a2;
    int b2 = p - TRI(a2);
    int ib2 = kb + 1 + a2, jb2 = kb + 1 + b2;
    int k0 = kb * 32;

    {
        int r = tid >> 3, cq = (tid & 7) * 4;
        *(float4*)&As[r][cq] = *(const float4*)&Lg[PAD(ib2 * 32 + r) + k0 + cq];
        *(float4*)&Bs[r][cq] = *(const float4*)&Lg[PAD(jb2 * 32 + r) + k0 + cq];
    }
    __syncthreads();

    int r2 = (tid >> 4) * 2, c2 = (tid & 15) * 2;
    float t00 = 0, t01 = 0, t10 = 0, t11 = 0;
#pragma unroll 8
    for (int q = 0; q < 32; ++q) {
        float a0 = As[r2][q], a1 = As[r2 + 1][q];
        float b0 = Bs[c2][q], b1 = Bs[c2 + 1][q];
        t00 += a0 * b0; t01 += a0 * b1;
        t10 += a1 * b0; t11 += a1 * b1;
    }
    int gi = ib2 * 32 + r2, gj = jb2 * 32 + c2;
    if (ib2 != jb2) {
        float* p0 = &Lg[PAD(gi) + gj];
        float* p1 = &Lg[PAD(gi + 1) + gj];
        p0[0] -= t00; p0[1] -= t01;
        p1[0] -= t10; p1[1] -= t11;
    } else {
        if (c2     <= r2    ) Lg[PAD(gi) + gj]         -= t00;
        if (c2 + 1 <= r2    ) Lg[PAD(gi) + gj + 1]     -= t01;
        if (c2     <= r2 + 1) Lg[PAD(gi + 1) + gj]     -= t10;
        if (c2 + 1 <= r2 + 1) Lg[PAD(gi + 1) + gj + 1] -= t11;
    }
}

// ---------------- K3d: blocked inverse + packed fragment-major bf16 epilogue ----------------
__global__ __launch_bounds__(256) void k_inv(const float* __restrict__ Lg,
                                             const float* __restrict__ sums,
                                             const float* __restrict__ gamma,
                                             unsigned short* __restrict__ Wphi,
                                             unsigned short* __restrict__ Wplo,
                                             float* __restrict__ biasacc) {
    __shared__ __align__(16) float Wcol[256][36];
    __shared__ __align__(16) float Ls[32][36];
    __shared__ __align__(16) float Tst[32][36];
    int jbb = blockIdx.x;      // 0..7 == kcg
    int tid = threadIdx.x;
    int j0 = jbb * 32;

    {
        int r = tid >> 3, cq = (tid & 7) * 4;
        const float* row = &Lg[PAD(j0 + r) + j0];
        float4 v;
        v.x = (cq     <= r) ? row[cq]     : 0.f;
        v.y = (cq + 1 <= r) ? row[cq + 1] : 0.f;
        v.z = (cq + 2 <= r) ? row[cq + 2] : 0.f;
        v.w = (cq + 3 <= r) ? row[cq + 3] : 0.f;
        *(float4*)&Wcol[j0 + r][cq] = v;
    }
    __syncthreads();

    int r2 = (tid >> 4) * 2, c2 = (tid & 15) * 2;
    for (int ib = jbb + 1; ib < 8; ++ib) {
        int i0 = ib * 32;
        float t00 = 0, t01 = 0, t10 = 0, t11 = 0;
        for (int kb = jbb; kb < ib; ++kb) {
            __syncthreads();
            {
                int r = tid >> 3, cq = (tid & 7) * 4;
                *(float4*)&Ls[r][cq] = *(const float4*)&Lg[PAD(i0 + r) + kb * 32 + cq];
            }
            __syncthreads();
            int kw = kb * 32;
#pragma unroll 8
            for (int q = 0; q < 32; ++q) {
                float l0 = Ls[r2][q], l1 = Ls[r2 + 1][q];
                float w0 = Wcol[kw + q][c2], w1 = Wcol[kw + q][c2 + 1];
                t00 += l0 * w0; t01 += l0 * w1;
                t10 += l1 * w0; t11 += l1 * w1;
            }
        }
        __syncthreads();
        Tst[r2][c2] = t00;     Tst[r2][c2 + 1] = t01;
        Tst[r2 + 1][c2] = t10; Tst[r2 + 1][c2 + 1] = t11;
        {
            int r = tid >> 3, cq = (tid & 7) * 4;
            const float* row = &Lg[PAD(i0 + r) + i0];
            float4 v;
            v.x = (cq     <= r) ? row[cq]     : 0.f;
            v.y = (cq + 1 <= r) ? row[cq + 1] : 0.f;
            v.z = (cq + 2 <= r) ? row[cq + 2] : 0.f;
            v.w = (cq + 3 <= r) ? row[cq + 3] : 0.f;
            *(float4*)&Ls[r][cq] = v;
        }
        __syncthreads();
        float w00 = 0, w01 = 0, w10 = 0, w11 = 0;
#pragma unroll 8
        for (int q = 0; q < 32; ++q) {
            float d0 = Ls[r2][q], d1 = Ls[r2 + 1][q];
            float tq0 = Tst[q][c2], tq1 = Tst[q][c2 + 1];
            w00 += d0 * tq0; w01 += d0 * tq1;
            w10 += d1 * tq0; w11 += d1 * tq1;
        }
        Wcol[i0 + r2][c2] = -w00;     Wcol[i0 + r2][c2 + 1] = -w01;
        Wcol[i0 + r2 + 1][c2] = -w10; Wcol[i0 + r2 + 1][c2 + 1] = -w11;
    }
    __syncthreads();

    {
        int r = tid;
        if (r >= j0) {
            float s = 0.f;
#pragma unroll 8
            for (int c = 0; c < 32; ++c)
                s += Wcol[r][c] * sums[j0 + c];
            atomicAdd(&biasacc[r], s * (1.f / (float)NROWS));
        }
    }
    // packed fragment-major epilogue: Wp[((jt*8 + jbb)*64 + l)*8 + j]
    for (int pi = tid; pi < 1024; pi += 256) {
        int jt = pi >> 6, l = pi & 63;
        int row = jt * 16 + (l & 15);
        int cb = (l >> 4) * 8;
        float g = (row >= j0) ? gamma[row] : 0.f;
        u16x4 h0, h1, lo0, lo1;
#pragma unroll
        for (int j = 0; j < 8; ++j) {
            float v = (row >= j0) ? g * Wcol[row][cb + j] : 0.f;
            unsigned b = __float_as_uint(v);
            unsigned short hi = (unsigned short)(b >> 16);
            float lf = v - __uint_as_float(b & 0xFFFF0000u);
            unsigned short lo = (unsigned short)(__float_as_uint(lf) >> 16);
            if (j < 4) { h0[j] = hi; lo0[j] = lo; }
            else       { h1[j - 4] = hi; lo1[j - 4] = lo; }
        }
        size_t base = ((size_t)(jt * 8 + jbb) * 64 + l) * 8;
        *(u16x4*)&Wphi[base]     = h0;
        *(u16x4*)&Wphi[base + 4] = h1;
        *(u16x4*)&Wplo[base]     = lo0;
        *(u16x4*)&Wplo[base + 4] = lo1;
    }
}

// ---------------- K4: out = bf16(x) * Wg^T + bias, 8 waves x 16 rows for TLP ----------------
#define ASTR 264   // ushorts per LDS row (528B)
__global__ __launch_bounds__(512) void k_apply(const float* __restrict__ x,
                                               const unsigned short* __restrict__ Wphi,
                                               const unsigned short* __restrict__ Wplo,
                                               const float* __restrict__ beta,
                                               const float* __restrict__ gamma,
                                               const float* __restrict__ biasacc,
                                               float* __restrict__ out) {
    __shared__ unsigned short Ah[128 * ASTR];   // 66 KB
    int tid = threadIdx.x, wave = tid >> 6, lane = tid & 63;
    int m = lane & 15, kg = lane >> 4;
    size_t rblk = (size_t)blockIdx.x * 128;
    size_t rbase = rblk + wave * 16;

    // stage full 128x256 x-tile as RNE-rounded bf16, fully coalesced
#pragma unroll
    for (int it = 0; it < 16; ++it) {
        int f = it * 512 + tid;          // 0..8191 float4-groups
        int row = f >> 6, c4 = f & 63;
        f32x4 v = *(const f32x4*)&x[(rblk + row) * 256 + c4 * 4];
        u16x4 h;
#pragma unroll
        for (int e = 0; e < 4; ++e) {
            unsigned b = __float_as_uint(v[e]);
            b += 0x7FFFu + ((b >> 16) & 1u);   // round-to-nearest-even
            h[e] = (unsigned short)(b >> 16);
        }
        *(u16x4*)&Ah[row * ASTR + c4 * 4] = h;
    }
    __syncthreads();

    f32x4 acc[16];
#pragma unroll
    for (int t = 0; t < 16; ++t) acc[t] = 0.f;

    int arow = (wave * 16 + m) * ASTR + kg * 8;
#pragma unroll
    for (int kcg = 0; kcg < 8; ++kcg) {
        bf16x8 ah = *(const bf16x8*)&Ah[arow + kcg * 32];
#pragma unroll
        for (int jt = 0; jt < 16; ++jt) {
            size_t wo = ((size_t)(jt * 8 + kcg) * 64 + lane) * 8;  // contiguous 1KB/wave
            bf16x8 bh = *(const bf16x8*)&Wphi[wo];
            bf16x8 bl = *(const bf16x8*)&Wplo[wo];
            acc[jt] = MFMA16(ah, bh, acc[jt], 0, 0, 0);
            acc[jt] = MFMA16(ah, bl, acc[jt], 0, 0, 0);
        }
    }

#pragma unroll
    for (int jt = 0; jt < 16; ++jt) {
        int j = jt * 16 + m;
        float bb = beta[j] - gamma[j] * biasacc[j];
#pragma unroll
        for (int q = 0; q < 4; ++q)
            out[(rbase + kg * 4 + q) * 256 + j] = acc[jt][q] + bb;
    }
}

extern "C" void kernel_launch(void* const* d_in, const int* in_sizes, int n_in,
                              void* d_out, int out_size, void* d_ws, size_t ws_size,
                              hipStream_t stream) {
    const float* x     = (const float*)d_in[0];
    const float* gamma = (const float*)d_in[1];
    const float* beta  = (const float*)d_in[2];
    float* out  = (float*)d_out;
    float* ws   = (float*)d_ws;
    float* sums     = ws;                 // 256
    float* biasacc  = ws + 256;           // 256
    float* S8       = ws + 512;           // 8*65536
    float* Lg       = ws + 524800;        // 33280
    unsigned short* Wphi = (unsigned short*)(ws + 558080);   // 65536 bf16
    unsigned short* Wplo = (unsigned short*)(ws + 590848);   // 65536 bf16

    hipMemsetAsync(ws, 0, 524800 * sizeof(float), stream);
    hipLaunchKernelGGL(k_cov, dim3(448), dim3(256), 0, stream, x, S8, sums);
    hipLaunchKernelGGL(k_init, dim3(64), dim3(256), 0, stream, S8, sums, Lg);
    for (int kb = 0; kb < 8; ++kb) {
        hipLaunchKernelGGL(k_panel, dim3(1), dim3(512), 0, stream, Lg, kb);
        int np = TRI(7 - kb);
        if (np > 0)
            hipLaunchKernelGGL(k_trail, dim3(np), dim3(256), 0, stream, Lg, kb);
    }
    hipLaunchKernelGGL(k_inv, dim3(8), dim3(256), 0, stream, Lg, sums, gamma, Wphi, Wplo, biasacc);
    hipLaunchKernelGGL(k_apply, dim3(1568), dim3(512), 0, stream, x, Wphi, Wplo, beta, gamma, biasacc, out);
}

// Round 13
// 660.550 us; speedup vs baseline: 1.3989x; 1.0949x over previous
//
#include <hip/hip_runtime.h>
#include <hip/hip_bf16.h>
#include <math.h>

#define C 256
#define NROWS (64*56*56)   // 200704
#define EPSV 0.001f
#define TRI(i) (((i)*((i)+1))>>1)

typedef __attribute__((ext_vector_type(8))) short bf16x8;
typedef __attribute__((ext_vector_type(4))) float f32x4;
typedef __attribute__((ext_vector_type(4))) unsigned short u16x4;
#define MFMA16 __builtin_amdgcn_mfma_f32_16x16x32_bf16

// padded packed-lower-triangle layout: row i starts at PAD(i), rows rounded to 4 floats
__device__ __forceinline__ int PAD(int i) {
    int a = i >> 2, b = i & 3;
    return ((a + 1) * (2 * a + b)) << 2;
}

__device__ __forceinline__ float bcastf(float v, int l) {
    return __int_as_float(__builtin_amdgcn_readlane(__float_as_int(v), l));
}

__device__ __forceinline__ void split2(float v0, float v1, unsigned& hi, unsigned& lo) {
    unsigned b0 = __float_as_uint(v0), b1 = __float_as_uint(v1);
    hi = (b0 >> 16) | (b1 & 0xFFFF0000u);
    float l0 = v0 - __uint_as_float(b0 & 0xFFFF0000u);
    float l1 = v1 - __uint_as_float(b1 & 0xFFFF0000u);
    lo = (__float_as_uint(l0) >> 16) | (__float_as_uint(l1) & 0xFFFF0000u);
}

// ws layout (floats):
//  [0,256)          : channel sums
//  [256,512)        : biasacc
//  [512,524800)     : S8 = 8 copies of S partials (8*65536)
//  [524800,558080)  : Lg  = factored triangle
//  [558080,590848)  : Wphi (packed fragment-major bf16, 65536 ushort)
//  [590848,623616)  : Wplo

// ---------------- K2: S = X^T X via bf16-split MFMA, 8 waves x 17 tiles ----------------
// Wave W owns lower-tri 16x16 tile-rows {W, 15-W} (17 tiles, static indexing).
// LDS: stride 20 u32 per channel row, 16B-chunk XOR swizzle key = (row>>3)&3.
template<int W>
__device__ __forceinline__ void cov_step(f32x4* acc, const unsigned* lh, const unsigned* ll,
                                         int m, int kg) {
    constexpr int R0 = W, R1 = 15 - W;
    constexpr int O1 = W + 1;
    bf16x8 ah[2], al[2];
    {
        int r0 = R0 * 16 + m, r1 = R1 * 16 + m;
        int o0 = r0 * 20 + ((kg ^ ((r0 >> 3) & 3)) << 2);
        int o1 = r1 * 20 + ((kg ^ ((r1 >> 3) & 3)) << 2);
        ah[0] = *(const bf16x8*)&lh[o0]; al[0] = *(const bf16x8*)&ll[o0];
        ah[1] = *(const bf16x8*)&lh[o1]; al[1] = *(const bf16x8*)&ll[o1];
    }
#pragma unroll
    for (int c = 0; c <= R1; ++c) {
        int rb = c * 16 + m;
        int ob = rb * 20 + ((kg ^ ((rb >> 3) & 3)) << 2);
        bf16x8 bh = *(const bf16x8*)&lh[ob];
        bf16x8 bl = *(const bf16x8*)&ll[ob];
        if (c <= R0) {
            acc[c] = MFMA16(ah[0], bh, acc[c], 0, 0, 0);
            acc[c] = MFMA16(ah[0], bl, acc[c], 0, 0, 0);
            acc[c] = MFMA16(al[0], bh, acc[c], 0, 0, 0);
        }
        {
            acc[O1 + c] = MFMA16(ah[1], bh, acc[O1 + c], 0, 0, 0);
            acc[O1 + c] = MFMA16(ah[1], bl, acc[O1 + c], 0, 0, 0);
            acc[O1 + c] = MFMA16(al[1], bh, acc[O1 + c], 0, 0, 0);
        }
    }
}

template<int W>
__device__ __forceinline__ void cov_out(const f32x4* acc, float* Sc, int m, int kg) {
    constexpr int R[2] = {W, 15 - W};
    constexpr int O[2] = {0, W + 1};
#pragma unroll
    for (int rr = 0; rr < 2; ++rr) {
        int i0 = R[rr] * 16 + kg * 4;
#pragma unroll
        for (int c = 0; c < 16; ++c) {
            if (c <= R[rr]) {
                int j = c * 16 + m;
#pragma unroll
                for (int q = 0; q < 4; ++q)
                    atomicAdd(&Sc[(i0 + q) * 256 + j], acc[O[rr] + c][q]);
            }
        }
    }
}

__global__ __launch_bounds__(512, 4) void k_cov(const float* __restrict__ x,
                                                float* __restrict__ S8,
                                                float* __restrict__ sums) {
    __shared__ unsigned lh[256 * 20];    // 20 KB
    __shared__ unsigned ll_[256 * 20];   // 20 KB
    int tid = threadIdx.x, wave = tid >> 6, lane = tid & 63;
    int m = lane & 15, kg = lane >> 4;
    int ch = tid & 255, half = tid >> 8;
    const float* xc = x + (size_t)blockIdx.x * 448 * 256 + ch;
    f32x4 acc[17];
#pragma unroll
    for (int t = 0; t < 17; ++t) acc[t] = 0.f;
    float colsum = 0.f;
    int swkey = (ch >> 3) & 3;

    for (int it = 0; it < 14; ++it) {
        __syncthreads();
        const float* xr = xc + it * 32 * 256;
#pragma unroll
        for (int j = 0; j < 8; ++j) {
            int rp = half * 8 + j;
            float v0 = xr[(2 * rp) * 256];
            float v1 = xr[(2 * rp + 1) * 256];
            colsum += v0 + v1;
            unsigned h, l;
            split2(v0, v1, h, l);
            int idx = ch * 20 + ((((rp >> 2) ^ swkey) << 2) | (rp & 3));
            lh[idx] = h;
            ll_[idx] = l;
        }
        __syncthreads();
        switch (wave) {
            case 0: cov_step<0>(acc, lh, ll_, m, kg); break;
            case 1: cov_step<1>(acc, lh, ll_, m, kg); break;
            case 2: cov_step<2>(acc, lh, ll_, m, kg); break;
            case 3: cov_step<3>(acc, lh, ll_, m, kg); break;
            case 4: cov_step<4>(acc, lh, ll_, m, kg); break;
            case 5: cov_step<5>(acc, lh, ll_, m, kg); break;
            case 6: cov_step<6>(acc, lh, ll_, m, kg); break;
            default: cov_step<7>(acc, lh, ll_, m, kg); break;
        }
    }
    atomicAdd(&sums[ch], colsum);
    float* Sc = S8 + (size_t)(blockIdx.x & 7) * 65536;
    switch (wave) {
        case 0: cov_out<0>(acc, Sc, m, kg); break;
        case 1: cov_out<1>(acc, Sc, m, kg); break;
        case 2: cov_out<2>(acc, Sc, m, kg); break;
        case 3: cov_out<3>(acc, Sc, m, kg); break;
        case 4: cov_out<4>(acc, Sc, m, kg); break;
        case 5: cov_out<5>(acc, Sc, m, kg); break;
        case 6: cov_out<6>(acc, Sc, m, kg); break;
        default: cov_out<7>(acc, Sc, m, kg); break;
    }
}

// ---------------- K3a: init triangle from S8 partials ----------------
__global__ __launch_bounds__(256) void k_init(const float* __restrict__ S8,
                                              const float* __restrict__ sums,
                                              float* __restrict__ Lg) {
    int u = blockIdx.x * 256 + threadIdx.x;   // 0..16383
    int i = u >> 6, j0 = (u & 63) << 2;
    if (j0 > i) return;
    const float scale = (1.f - EPSV) / ((float)NROWS - 1.f);
    f32x4 s4 = 0.f;
#pragma unroll
    for (int p = 0; p < 8; ++p)
        s4 += *(const f32x4*)&S8[p * 65536 + i * C + j0];
    float mi = sums[i] * (1.f / (float)NROWS);
    f32x4 mj = *(const f32x4*)&sums[j0];
    int base = PAD(i);
#pragma unroll
    for (int e = 0; e < 4; ++e) {
        int j = j0 + e;
        if (j <= i) {
            float v = (s4[e] - mi * mj[e]) * scale;
            if (j == i) v += EPSV;
            Lg[base + j] = v;
        }
    }
}

// ---------------- K3b: per-panel diag factor + inverse + panel solve (1 block) ----------------
__global__ __launch_bounds__(512) void k_panel(float* __restrict__ Lg, int kb) {
    __shared__ __align__(16) float DS[32 * 36];
    int tid = threadIdx.x;
    int lane = tid & 63;
    int k0 = kb * 32;

    if (tid < 64) {
        int col = lane & 31;
        float a[32];
#pragma unroll
        for (int i = 0; i < 32; ++i) {
            int ii = (i >= col) ? i : col;
            int jj = (i >= col) ? col : i;
            a[i] = Lg[PAD(k0 + ii) + k0 + jj];
        }
        float drec = 0.f;
#pragma unroll
        for (int k = 0; k < 32; ++k) {
            float akk = bcastf(a[k], k);
            float rinv = rsqrtf(akk);
            float myl = a[k] * rinv;
            bool up = (col > k);
#pragma unroll
            for (int i = k + 1; i < 32; ++i) {
                float lik = bcastf(a[i], k) * rinv;
                if (up) a[i] -= lik * myl;
                if (col == k) a[i] = lik;
            }
            if (col == k) { a[k] = akk * rinv; drec = rinv; }
        }
        float xv[32];
#pragma unroll
        for (int i = 0; i < 32; ++i) xv[i] = (col == i) ? 1.f : 0.f;
#pragma unroll
        for (int i = 0; i < 32; ++i) {
            float di = bcastf(drec, i);
            float xi = xv[i] * di;
            xv[i] = xi;
#pragma unroll
            for (int j = i + 1; j < 32; ++j) {
                float lji = bcastf(a[j], i);
                xv[j] -= lji * xi;
            }
        }
        if (lane < 32) {
#pragma unroll
            for (int i = 0; i < 32; ++i) {
                DS[i * 36 + col] = xv[i];
                if (i >= col) Lg[PAD(k0 + i) + k0 + col] = xv[i];
            }
        }
    }
    __syncthreads();

    int m = 224 - k0;
    int r = tid >> 1, g = tid & 1;
    if (r < m) {
        int abase = PAD(k0 + 32 + r) + k0;
        float4 av[8];
#pragma unroll
        for (int q = 0; q < 8; ++q) av[q] = *(const float4*)&Lg[abase + q * 4];
#pragma unroll
        for (int tgrp = 0; tgrp < 4; ++tgrp) {
            int cbase = g * 16 + tgrp * 4;
            float rv[4];
#pragma unroll
            for (int cc = 0; cc < 4; ++cc) {
                const float* drow = &DS[(cbase + cc) * 36];
                float s = 0.f;
#pragma unroll
                for (int q = 0; q < 8; ++q) {
                    float4 d4 = *(const float4*)&drow[q * 4];
                    s += av[q].x*d4.x + av[q].y*d4.y + av[q].z*d4.z + av[q].w*d4.w;
                }
                rv[cc] = s;
            }
            float4 res; res.x = rv[0]; res.y = rv[1]; res.z = rv[2]; res.w = rv[3];
            *(float4*)&Lg[abase + cbase] = res;
        }
    }
}

// ---------------- K3c: trailing update, one 32x32 block-pair per workgroup ----------------
__global__ __launch_bounds__(256) void k_trail(float* __restrict__ Lg, int kb) {
    __shared__ __align__(16) float As[32][36];
    __shared__ __align__(16) float Bs[32][36];
    int tid = threadIdx.x;
    int p = blockIdx.x;
    int a2 = 0;
    while (TRI(a2 + 1) <= p) ++a2;
    int b2 = p - TRI(a2);
    int ib2 = kb + 1 + a2, jb2 = kb + 1 + b2;
    int k0 = kb * 32;

    {
        int r = tid >> 3, cq = (tid & 7) * 4;
        *(float4*)&As[r][cq] = *(const float4*)&Lg[PAD(ib2 * 32 + r) + k0 + cq];
        *(float4*)&Bs[r][cq] = *(const float4*)&Lg[PAD(jb2 * 32 + r) + k0 + cq];
    }
    __syncthreads();

    int r2 = (tid >> 4) * 2, c2 = (tid & 15) * 2;
    float t00 = 0, t01 = 0, t10 = 0, t11 = 0;
#pragma unroll 8
    for (int q = 0; q < 32; ++q) {
        float a0 = As[r2][q], a1 = As[r2 + 1][q];
        float b0 = Bs[c2][q], b1 = Bs[c2 + 1][q];
        t00 += a0 * b0; t01 += a0 * b1;
        t10 += a1 * b0; t11 += a1 * b1;
    }
    int gi = ib2 * 32 + r2, gj = jb2 * 32 + c2;
    if (ib2 != jb2) {
        float* p0 = &Lg[PAD(gi) + gj];
        float* p1 = &Lg[PAD(gi + 1) + gj];
        p0[0] -= t00; p0[1] -= t01;
        p1[0] -= t10; p1[1] -= t11;
    } else {
        if (c2     <= r2    ) Lg[PAD(gi) + gj]         -= t00;
        if (c2 + 1 <= r2    ) Lg[PAD(gi) + gj + 1]     -= t01;
        if (c2     <= r2 + 1) Lg[PAD(gi + 1) + gj]     -= t10;
        if (c2 + 1 <= r2 + 1) Lg[PAD(gi + 1) + gj + 1] -= t11;
    }
}

// ---------------- K3d: blocked inverse + packed fragment-major bf16 epilogue ----------------
__global__ __launch_bounds__(256) void k_inv(const float* __restrict__ Lg,
                                             const float* __restrict__ sums,
                                             const float* __restrict__ gamma,
                                             unsigned short* __restrict__ Wphi,
                                             unsigned short* __restrict__ Wplo,
                                             float* __restrict__ biasacc) {
    __shared__ __align__(16) float Wcol[256][36];
    __shared__ __align__(16) float Ls[32][36];
    __shared__ __align__(16) float Tst[32][36];
    int jbb = blockIdx.x;      // 0..7 == kcg
    int tid = threadIdx.x;
    int j0 = jbb * 32;

    {
        int r = tid >> 3, cq = (tid & 7) * 4;
        const float* row = &Lg[PAD(j0 + r) + j0];
        float4 v;
        v.x = (cq     <= r) ? row[cq]     : 0.f;
        v.y = (cq + 1 <= r) ? row[cq + 1] : 0.f;
        v.z = (cq + 2 <= r) ? row[cq + 2] : 0.f;
        v.w = (cq + 3 <= r) ? row[cq + 3] : 0.f;
        *(float4*)&Wcol[j0 + r][cq] = v;
    }
    __syncthreads();

    int r2 = (tid >> 4) * 2, c2 = (tid & 15) * 2;
    for (int ib = jbb + 1; ib < 8; ++ib) {
        int i0 = ib * 32;
        float t00 = 0, t01 = 0, t10 = 0, t11 = 0;
        for (int kb = jbb; kb < ib; ++kb) {
            __syncthreads();
            {
                int r = tid >> 3, cq = (tid & 7) * 4;
                *(float4*)&Ls[r][cq] = *(const float4*)&Lg[PAD(i0 + r) + kb * 32 + cq];
            }
            __syncthreads();
            int kw = kb * 32;
#pragma unroll 8
            for (int q = 0; q < 32; ++q) {
                float l0 = Ls[r2][q], l1 = Ls[r2 + 1][q];
                float w0 = Wcol[kw + q][c2], w1 = Wcol[kw + q][c2 + 1];
                t00 += l0 * w0; t01 += l0 * w1;
                t10 += l1 * w0; t11 += l1 * w1;
            }
        }
        __syncthreads();
        Tst[r2][c2] = t00;     Tst[r2][c2 + 1] = t01;
        Tst[r2 + 1][c2] = t10; Tst[r2 + 1][c2 + 1] = t11;
        {
            int r = tid >> 3, cq = (tid & 7) * 4;
            const float* row = &Lg[PAD(i0 + r) + i0];
            float4 v;
            v.x = (cq     <= r) ? row[cq]     : 0.f;
            v.y = (cq + 1 <= r) ? row[cq + 1] : 0.f;
            v.z = (cq + 2 <= r) ? row[cq + 2] : 0.f;
            v.w = (cq + 3 <= r) ? row[cq + 3] : 0.f;
            *(float4*)&Ls[r][cq] = v;
        }
        __syncthreads();
        float w00 = 0, w01 = 0, w10 = 0, w11 = 0;
#pragma unroll 8
        for (int q = 0; q < 32; ++q) {
            float d0 = Ls[r2][q], d1 = Ls[r2 + 1][q];
            float tq0 = Tst[q][c2], tq1 = Tst[q][c2 + 1];
            w00 += d0 * tq0; w01 += d0 * tq1;
            w10 += d1 * tq0; w11 += d1 * tq1;
        }
        Wcol[i0 + r2][c2] = -w00;     Wcol[i0 + r2][c2 + 1] = -w01;
        Wcol[i0 + r2 + 1][c2] = -w10; Wcol[i0 + r2 + 1][c2 + 1] = -w11;
    }
    __syncthreads();

    {
        int r = tid;
        if (r >= j0) {
            float s = 0.f;
#pragma unroll 8
            for (int c = 0; c < 32; ++c)
                s += Wcol[r][c] * sums[j0 + c];
            atomicAdd(&biasacc[r], s * (1.f / (float)NROWS));
        }
    }
    // packed fragment-major epilogue: Wp[((jt*8 + jbb)*64 + l)*8 + j]
    for (int pi = tid; pi < 1024; pi += 256) {
        int jt = pi >> 6, l = pi & 63;
        int row = jt * 16 + (l & 15);
        int cb = (l >> 4) * 8;
        float g = (row >= j0) ? gamma[row] : 0.f;
        u16x4 h0, h1, lo0, lo1;
#pragma unroll
        for (int j = 0; j < 8; ++j) {
            float v = (row >= j0) ? g * Wcol[row][cb + j] : 0.f;
            unsigned b = __float_as_uint(v);
            unsigned short hi = (unsigned short)(b >> 16);
            float lf = v - __uint_as_float(b & 0xFFFF0000u);
            unsigned short lo = (unsigned short)(__float_as_uint(lf) >> 16);
            if (j < 4) { h0[j] = hi; lo0[j] = lo; }
            else       { h1[j - 4] = hi; lo1[j - 4] = lo; }
        }
        size_t base = ((size_t)(jt * 8 + jbb) * 64 + l) * 8;
        *(u16x4*)&Wphi[base]     = h0;
        *(u16x4*)&Wphi[base + 4] = h1;
        *(u16x4*)&Wplo[base]     = lo0;
        *(u16x4*)&Wplo[base + 4] = lo1;
    }
}

// ---------------- K4: out = bf16(x) * Wg^T + bias, 8 waves x 16 rows for TLP ----------------
#define ASTR 264   // ushorts per LDS row (528B)
__global__ __launch_bounds__(512) void k_apply(const float* __restrict__ x,
                                               const unsigned short* __restrict__ Wphi,
                                               const unsigned short* __restrict__ Wplo,
                                               const float* __restrict__ beta,
                                               const float* __restrict__ gamma,
                                               const float* __restrict__ biasacc,
                                               float* __restrict__ out) {
    __shared__ unsigned short Ah[128 * ASTR];   // 66 KB
    int tid = threadIdx.x, wave = tid >> 6, lane = tid & 63;
    int m = lane & 15, kg = lane >> 4;
    size_t rblk = (size_t)blockIdx.x * 128;
    size_t rbase = rblk + wave * 16;

    // stage full 128x256 x-tile as RNE-rounded bf16, fully coalesced
#pragma unroll
    for (int it = 0; it < 16; ++it) {
        int f = it * 512 + tid;          // 0..8191 float4-groups
        int row = f >> 6, c4 = f & 63;
        f32x4 v = *(const f32x4*)&x[(rblk + row) * 256 + c4 * 4];
        u16x4 h;
#pragma unroll
        for (int e = 0; e < 4; ++e) {
            unsigned b = __float_as_uint(v[e]);
            b += 0x7FFFu + ((b >> 16) & 1u);   // round-to-nearest-even
            h[e] = (unsigned short)(b >> 16);
        }
        *(u16x4*)&Ah[row * ASTR + c4 * 4] = h;
    }
    __syncthreads();

    f32x4 acc[16];
#pragma unroll
    for (int t = 0; t < 16; ++t) acc[t] = 0.f;

    int arow = (wave * 16 + m) * ASTR + kg * 8;
#pragma unroll
    for (int kcg = 0; kcg < 8; ++kcg) {
        bf16x8 ah = *(const bf16x8*)&Ah[arow + kcg * 32];
#pragma unroll
        for (int jt = 0; jt < 16; ++jt) {
            size_t wo = ((size_t)(jt * 8 + kcg) * 64 + lane) * 8;  // contiguous 1KB/wave
            bf16x8 bh = *(const bf16x8*)&Wphi[wo];
            bf16x8 bl = *(const bf16x8*)&Wplo[wo];
            acc[jt] = MFMA16(ah, bh, acc[jt], 0, 0, 0);
            acc[jt] = MFMA16(ah, bl, acc[jt], 0, 0, 0);
        }
    }

#pragma unroll
    for (int jt = 0; jt < 16; ++jt) {
        int j = jt * 16 + m;
        float bb = beta[j] - gamma[j] * biasacc[j];
#pragma unroll
        for (int q = 0; q < 4; ++q)
            out[(rbase + kg * 4 + q) * 256 + j] = acc[jt][q] + bb;
    }
}

extern "C" void kernel_launch(void* const* d_in, const int* in_sizes, int n_in,
                              void* d_out, int out_size, void* d_ws, size_t ws_size,
                              hipStream_t stream) {
    const float* x     = (const float*)d_in[0];
    const float* gamma = (const float*)d_in[1];
    const float* beta  = (const float*)d_in[2];
    float* out  = (float*)d_out;
    float* ws   = (float*)d_ws;
    float* sums     = ws;                 // 256
    float* biasacc  = ws + 256;           // 256
    float* S8       = ws + 512;           // 8*65536
    float* Lg       = ws + 524800;        // 33280
    unsigned short* Wphi = (unsigned short*)(ws + 558080);   // 65536 bf16
    unsigned short* Wplo = (unsigned short*)(ws + 590848);   // 65536 bf16

    hipMemsetAsync(ws, 0, 524800 * sizeof(float), stream);
    hipLaunchKernelGGL(k_cov, dim3(448), dim3(512), 0, stream, x, S8, sums);
    hipLaunchKernelGGL(k_init, dim3(64), dim3(256), 0, stream, S8, sums, Lg);
    for (int kb = 0; kb < 8; ++kb) {
        hipLaunchKernelGGL(k_panel, dim3(1), dim3(512), 0, stream, Lg, kb);
        int np = TRI(7 - kb);
        if (np > 0)
            hipLaunchKernelGGL(k_trail, dim3(np), dim3(256), 0, stream, Lg, kb);
    }
    hipLaunchKernelGGL(k_inv, dim3(8), dim3(256), 0, stream, Lg, sums, gamma, Wphi, Wplo, biasacc);
    hipLaunchKernelGGL(k_apply, dim3(1568), dim3(512), 0, stream, x, Wphi, Wplo, beta, gamma, biasacc, out);
}

// Round 14
// 617.724 us; speedup vs baseline: 1.4959x; 1.0693x over previous
//
#include <hip/hip_runtime.h>
#include <hip/hip_bf16.h>
#include <math.h>

#define C 256
#define NROWS (64*56*56)   // 200704
#define EPSV 0.001f
#define TRI(i) (((i)*((i)+1))>>1)

typedef __attribute__((ext_vector_type(8))) short bf16x8;
typedef __attribute__((ext_vector_type(4))) float f32x4;
typedef __attribute__((ext_vector_type(4))) unsigned short u16x4;
typedef __attribute__((ext_vector_type(8))) unsigned short u16x8;
#define MFMA16 __builtin_amdgcn_mfma_f32_16x16x32_bf16

// padded packed-lower-triangle layout: row i starts at PAD(i), rows rounded to 4 floats
__device__ __forceinline__ int PAD(int i) {
    int a = i >> 2, b = i & 3;
    return ((a + 1) * (2 * a + b)) << 2;
}

__device__ __forceinline__ float bcastf(float v, int l) {
    return __int_as_float(__builtin_amdgcn_readlane(__float_as_int(v), l));
}

__device__ __forceinline__ void split2(float v0, float v1, unsigned& hi, unsigned& lo) {
    unsigned b0 = __float_as_uint(v0), b1 = __float_as_uint(v1);
    hi = (b0 >> 16) | (b1 & 0xFFFF0000u);
    float l0 = v0 - __uint_as_float(b0 & 0xFFFF0000u);
    float l1 = v1 - __uint_as_float(b1 & 0xFFFF0000u);
    lo = (__float_as_uint(l0) >> 16) | (__float_as_uint(l1) & 0xFFFF0000u);
}

// ws layout (floats):
//  [0,256)          : channel sums
//  [256,512)        : biasacc
//  [512,524800)     : S8 = 8 copies of S partials (8*65536)
//  [524800,558080)  : Lg  = factored triangle
//  [558080,590848)  : Wphi (packed fragment-major bf16, 65536 ushort)
//  [590848,623616)  : Wplo

// ---------------- K2: S = X^T X via bf16-split MFMA, 8 waves x 17 tiles ----------------
template<int W>
__device__ __forceinline__ void cov_step(f32x4* acc, const unsigned* lh, const unsigned* ll,
                                         int m, int kg) {
    constexpr int R0 = W, R1 = 15 - W;
    constexpr int O1 = W + 1;
    bf16x8 ah[2], al[2];
    {
        int r0 = R0 * 16 + m, r1 = R1 * 16 + m;
        int o0 = r0 * 20 + ((kg ^ ((r0 >> 3) & 3)) << 2);
        int o1 = r1 * 20 + ((kg ^ ((r1 >> 3) & 3)) << 2);
        ah[0] = *(const bf16x8*)&lh[o0]; al[0] = *(const bf16x8*)&ll[o0];
        ah[1] = *(const bf16x8*)&lh[o1]; al[1] = *(const bf16x8*)&ll[o1];
    }
#pragma unroll
    for (int c = 0; c <= R1; ++c) {
        int rb = c * 16 + m;
        int ob = rb * 20 + ((kg ^ ((rb >> 3) & 3)) << 2);
        bf16x8 bh = *(const bf16x8*)&lh[ob];
        bf16x8 bl = *(const bf16x8*)&ll[ob];
        if (c <= R0) {
            acc[c] = MFMA16(ah[0], bh, acc[c], 0, 0, 0);
            acc[c] = MFMA16(ah[0], bl, acc[c], 0, 0, 0);
            acc[c] = MFMA16(al[0], bh, acc[c], 0, 0, 0);
        }
        {
            acc[O1 + c] = MFMA16(ah[1], bh, acc[O1 + c], 0, 0, 0);
            acc[O1 + c] = MFMA16(ah[1], bl, acc[O1 + c], 0, 0, 0);
            acc[O1 + c] = MFMA16(al[1], bh, acc[O1 + c], 0, 0, 0);
        }
    }
}

template<int W>
__device__ __forceinline__ void cov_out(const f32x4* acc, float* Sc, int m, int kg) {
    constexpr int R[2] = {W, 15 - W};
    constexpr int O[2] = {0, W + 1};
#pragma unroll
    for (int rr = 0; rr < 2; ++rr) {
        int i0 = R[rr] * 16 + kg * 4;
#pragma unroll
        for (int c = 0; c < 16; ++c) {
            if (c <= R[rr]) {
                int j = c * 16 + m;
#pragma unroll
                for (int q = 0; q < 4; ++q)
                    atomicAdd(&Sc[(i0 + q) * 256 + j], acc[O[rr] + c][q]);
            }
        }
    }
}

__global__ __launch_bounds__(512, 4) void k_cov(const float* __restrict__ x,
                                                float* __restrict__ S8,
                                                float* __restrict__ sums) {
    __shared__ unsigned lh[256 * 20];    // 20 KB
    __shared__ unsigned ll_[256 * 20];   // 20 KB
    int tid = threadIdx.x, wave = tid >> 6, lane = tid & 63;
    int m = lane & 15, kg = lane >> 4;
    int ch = tid & 255, half = tid >> 8;
    const float* xc = x + (size_t)blockIdx.x * 448 * 256 + ch;
    f32x4 acc[17];
#pragma unroll
    for (int t = 0; t < 17; ++t) acc[t] = 0.f;
    float colsum = 0.f;
    int swkey = (ch >> 3) & 3;

    for (int it = 0; it < 14; ++it) {
        __syncthreads();
        const float* xr = xc + it * 32 * 256;
#pragma unroll
        for (int j = 0; j < 8; ++j) {
            int rp = half * 8 + j;
            float v0 = xr[(2 * rp) * 256];
            float v1 = xr[(2 * rp + 1) * 256];
            colsum += v0 + v1;
            unsigned h, l;
            split2(v0, v1, h, l);
            int idx = ch * 20 + ((((rp >> 2) ^ swkey) << 2) | (rp & 3));
            lh[idx] = h;
            ll_[idx] = l;
        }
        __syncthreads();
        switch (wave) {
            case 0: cov_step<0>(acc, lh, ll_, m, kg); break;
            case 1: cov_step<1>(acc, lh, ll_, m, kg); break;
            case 2: cov_step<2>(acc, lh, ll_, m, kg); break;
            case 3: cov_step<3>(acc, lh, ll_, m, kg); break;
            case 4: cov_step<4>(acc, lh, ll_, m, kg); break;
            case 5: cov_step<5>(acc, lh, ll_, m, kg); break;
            case 6: cov_step<6>(acc, lh, ll_, m, kg); break;
            default: cov_step<7>(acc, lh, ll_, m, kg); break;
        }
    }
    atomicAdd(&sums[ch], colsum);
    float* Sc = S8 + (size_t)(blockIdx.x & 7) * 65536;
    switch (wave) {
        case 0: cov_out<0>(acc, Sc, m, kg); break;
        case 1: cov_out<1>(acc, Sc, m, kg); break;
        case 2: cov_out<2>(acc, Sc, m, kg); break;
        case 3: cov_out<3>(acc, Sc, m, kg); break;
        case 4: cov_out<4>(acc, Sc, m, kg); break;
        case 5: cov_out<5>(acc, Sc, m, kg); break;
        case 6: cov_out<6>(acc, Sc, m, kg); break;
        default: cov_out<7>(acc, Sc, m, kg); break;
    }
}

// ---------------- K3a: init triangle from S8 partials ----------------
__global__ __launch_bounds__(256) void k_init(const float* __restrict__ S8,
                                              const float* __restrict__ sums,
                                              float* __restrict__ Lg) {
    int u = blockIdx.x * 256 + threadIdx.x;   // 0..16383
    int i = u >> 6, j0 = (u & 63) << 2;
    if (j0 > i) return;
    const float scale = (1.f - EPSV) / ((float)NROWS - 1.f);
    f32x4 s4 = 0.f;
#pragma unroll
    for (int p = 0; p < 8; ++p)
        s4 += *(const f32x4*)&S8[p * 65536 + i * C + j0];
    float mi = sums[i] * (1.f / (float)NROWS);
    f32x4 mj = *(const f32x4*)&sums[j0];
    int base = PAD(i);
#pragma unroll
    for (int e = 0; e < 4; ++e) {
        int j = j0 + e;
        if (j <= i) {
            float v = (s4[e] - mi * mj[e]) * scale;
            if (j == i) v += EPSV;
            Lg[base + j] = v;
        }
    }
}

// ---------------- K3b: per-panel diag factor + inverse + panel solve (1 block) ----------------
__global__ __launch_bounds__(512) void k_panel(float* __restrict__ Lg, int kb) {
    __shared__ __align__(16) float DS[32 * 36];
    int tid = threadIdx.x;
    int lane = tid & 63;
    int k0 = kb * 32;

    if (tid < 64) {
        int col = lane & 31;
        float a[32];
#pragma unroll
        for (int i = 0; i < 32; ++i) {
            int ii = (i >= col) ? i : col;
            int jj = (i >= col) ? col : i;
            a[i] = Lg[PAD(k0 + ii) + k0 + jj];
        }
        float drec = 0.f;
#pragma unroll
        for (int k = 0; k < 32; ++k) {
            float akk = bcastf(a[k], k);
            float rinv = rsqrtf(akk);
            float myl = a[k] * rinv;
            bool up = (col > k);
#pragma unroll
            for (int i = k + 1; i < 32; ++i) {
                float lik = bcastf(a[i], k) * rinv;
                if (up) a[i] -= lik * myl;
                if (col == k) a[i] = lik;
            }
            if (col == k) { a[k] = akk * rinv; drec = rinv; }
        }
        float xv[32];
#pragma unroll
        for (int i = 0; i < 32; ++i) xv[i] = (col == i) ? 1.f : 0.f;
#pragma unroll
        for (int i = 0; i < 32; ++i) {
            float di = bcastf(drec, i);
            float xi = xv[i] * di;
            xv[i] = xi;
#pragma unroll
            for (int j = i + 1; j < 32; ++j) {
                float lji = bcastf(a[j], i);
                xv[j] -= lji * xi;
            }
        }
        if (lane < 32) {
#pragma unroll
            for (int i = 0; i < 32; ++i) {
                DS[i * 36 + col] = xv[i];
                if (i >= col) Lg[PAD(k0 + i) + k0 + col] = xv[i];
            }
        }
    }
    __syncthreads();

    int m = 224 - k0;
    int r = tid >> 1, g = tid & 1;
    if (r < m) {
        int abase = PAD(k0 + 32 + r) + k0;
        float4 av[8];
#pragma unroll
        for (int q = 0; q < 8; ++q) av[q] = *(const float4*)&Lg[abase + q * 4];
#pragma unroll
        for (int tgrp = 0; tgrp < 4; ++tgrp) {
            int cbase = g * 16 + tgrp * 4;
            float rv[4];
#pragma unroll
            for (int cc = 0; cc < 4; ++cc) {
                const float* drow = &DS[(cbase + cc) * 36];
                float s = 0.f;
#pragma unroll
                for (int q = 0; q < 8; ++q) {
                    float4 d4 = *(const float4*)&drow[q * 4];
                    s += av[q].x*d4.x + av[q].y*d4.y + av[q].z*d4.z + av[q].w*d4.w;
                }
                rv[cc] = s;
            }
            float4 res; res.x = rv[0]; res.y = rv[1]; res.z = rv[2]; res.w = rv[3];
            *(float4*)&Lg[abase + cbase] = res;
        }
    }
}

// ---------------- K3c: trailing update, one 32x32 block-pair per workgroup ----------------
__global__ __launch_bounds__(256) void k_trail(float* __restrict__ Lg, int kb) {
    __shared__ __align__(16) float As[32][36];
    __shared__ __align__(16) float Bs[32][36];
    int tid = threadIdx.x;
    int p = blockIdx.x;
    int a2 = 0;
    while (TRI(a2 + 1) <= p) ++a2;
    int b2 = p - TRI(a2);
    int ib2 = kb + 1 + a2, jb2 = kb + 1 + b2;
    int k0 = kb * 32;

    {
        int r = tid >> 3, cq = (tid & 7) * 4;
        *(float4*)&As[r][cq] = *(const float4*)&Lg[PAD(ib2 * 32 + r) + k0 + cq];
        *(float4*)&Bs[r][cq] = *(const float4*)&Lg[PAD(jb2 * 32 + r) + k0 + cq];
    }
    __syncthreads();

    int r2 = (tid >> 4) * 2, c2 = (tid & 15) * 2;
    float t00 = 0, t01 = 0, t10 = 0, t11 = 0;
#pragma unroll 8
    for (int q = 0; q < 32; ++q) {
        float a0 = As[r2][q], a1 = As[r2 + 1][q];
        float b0 = Bs[c2][q], b1 = Bs[c2 + 1][q];
        t00 += a0 * b0; t01 += a0 * b1;
        t10 += a1 * b0; t11 += a1 * b1;
    }
    int gi = ib2 * 32 + r2, gj = jb2 * 32 + c2;
    if (ib2 != jb2) {
        float* p0 = &Lg[PAD(gi) + gj];
        float* p1 = &Lg[PAD(gi + 1) + gj];
        p0[0] -= t00; p0[1] -= t01;
        p1[0] -= t10; p1[1] -= t11;
    } else {
        if (c2     <= r2    ) Lg[PAD(gi) + gj]         -= t00;
        if (c2 + 1 <= r2    ) Lg[PAD(gi) + gj + 1]     -= t01;
        if (c2     <= r2 + 1) Lg[PAD(gi + 1) + gj]     -= t10;
        if (c2 + 1 <= r2 + 1) Lg[PAD(gi + 1) + gj + 1] -= t11;
    }
}

// ---------------- K3d: blocked inverse + packed fragment-major bf16 epilogue ----------------
__global__ __launch_bounds__(256) void k_inv(const float* __restrict__ Lg,
                                             const float* __restrict__ sums,
                                             const float* __restrict__ gamma,
                                             unsigned short* __restrict__ Wphi,
                                             unsigned short* __restrict__ Wplo,
                                             float* __restrict__ biasacc) {
    __shared__ __align__(16) float Wcol[256][36];
    __shared__ __align__(16) float Ls[32][36];
    __shared__ __align__(16) float Tst[32][36];
    int jbb = blockIdx.x;      // 0..7 == kcg
    int tid = threadIdx.x;
    int j0 = jbb * 32;

    {
        int r = tid >> 3, cq = (tid & 7) * 4;
        const float* row = &Lg[PAD(j0 + r) + j0];
        float4 v;
        v.x = (cq     <= r) ? row[cq]     : 0.f;
        v.y = (cq + 1 <= r) ? row[cq + 1] : 0.f;
        v.z = (cq + 2 <= r) ? row[cq + 2] : 0.f;
        v.w = (cq + 3 <= r) ? row[cq + 3] : 0.f;
        *(float4*)&Wcol[j0 + r][cq] = v;
    }
    __syncthreads();

    int r2 = (tid >> 4) * 2, c2 = (tid & 15) * 2;
    for (int ib = jbb + 1; ib < 8; ++ib) {
        int i0 = ib * 32;
        float t00 = 0, t01 = 0, t10 = 0, t11 = 0;
        for (int kb = jbb; kb < ib; ++kb) {
            __syncthreads();
            {
                int r = tid >> 3, cq = (tid & 7) * 4;
                *(float4*)&Ls[r][cq] = *(const float4*)&Lg[PAD(i0 + r) + kb * 32 + cq];
            }
            __syncthreads();
            int kw = kb * 32;
#pragma unroll 8
            for (int q = 0; q < 32; ++q) {
                float l0 = Ls[r2][q], l1 = Ls[r2 + 1][q];
                float w0 = Wcol[kw + q][c2], w1 = Wcol[kw + q][c2 + 1];
                t00 += l0 * w0; t01 += l0 * w1;
                t10 += l1 * w0; t11 += l1 * w1;
            }
        }
        __syncthreads();
        Tst[r2][c2] = t00;     Tst[r2][c2 + 1] = t01;
        Tst[r2 + 1][c2] = t10; Tst[r2 + 1][c2 + 1] = t11;
        {
            int r = tid >> 3, cq = (tid & 7) * 4;
            const float* row = &Lg[PAD(i0 + r) + i0];
            float4 v;
            v.x = (cq     <= r) ? row[cq]     : 0.f;
            v.y = (cq + 1 <= r) ? row[cq + 1] : 0.f;
            v.z = (cq + 2 <= r) ? row[cq + 2] : 0.f;
            v.w = (cq + 3 <= r) ? row[cq + 3] : 0.f;
            *(float4*)&Ls[r][cq] = v;
        }
        __syncthreads();
        float w00 = 0, w01 = 0, w10 = 0, w11 = 0;
#pragma unroll 8
        for (int q = 0; q < 32; ++q) {
            float d0 = Ls[r2][q], d1 = Ls[r2 + 1][q];
            float tq0 = Tst[q][c2], tq1 = Tst[q][c2 + 1];
            w00 += d0 * tq0; w01 += d0 * tq1;
            w10 += d1 * tq0; w11 += d1 * tq1;
        }
        Wcol[i0 + r2][c2] = -w00;     Wcol[i0 + r2][c2 + 1] = -w01;
        Wcol[i0 + r2 + 1][c2] = -w10; Wcol[i0 + r2 + 1][c2 + 1] = -w11;
    }
    __syncthreads();

    {
        int r = tid;
        if (r >= j0) {
            float s = 0.f;
#pragma unroll 8
            for (int c = 0; c < 32; ++c)
                s += Wcol[r][c] * sums[j0 + c];
            atomicAdd(&biasacc[r], s * (1.f / (float)NROWS));
        }
    }
    // packed fragment-major epilogue: Wp[((jt*8 + jbb)*64 + l)*8 + j]
    for (int pi = tid; pi < 1024; pi += 256) {
        int jt = pi >> 6, l = pi & 63;
        int row = jt * 16 + (l & 15);
        int cb = (l >> 4) * 8;
        float g = (row >= j0) ? gamma[row] : 0.f;
        u16x4 h0, h1, lo0, lo1;
#pragma unroll
        for (int j = 0; j < 8; ++j) {
            float v = (row >= j0) ? g * Wcol[row][cb + j] : 0.f;
            unsigned b = __float_as_uint(v);
            unsigned short hi = (unsigned short)(b >> 16);
            float lf = v - __uint_as_float(b & 0xFFFF0000u);
            unsigned short lo = (unsigned short)(__float_as_uint(lf) >> 16);
            if (j < 4) { h0[j] = hi; lo0[j] = lo; }
            else       { h1[j - 4] = hi; lo1[j - 4] = lo; }
        }
        size_t base = ((size_t)(jt * 8 + jbb) * 64 + l) * 8;
        *(u16x4*)&Wphi[base]     = h0;
        *(u16x4*)&Wphi[base + 4] = h1;
        *(u16x4*)&Wplo[base]     = lo0;
        *(u16x4*)&Wplo[base + 4] = lo1;
    }
}

// ---------------- K4: out = bf16(x) * Wg^T + bias; B staged in LDS per kcg ----------------
__global__ __launch_bounds__(512) void k_apply(const float* __restrict__ x,
                                               const unsigned short* __restrict__ Wphi,
                                               const unsigned short* __restrict__ Wplo,
                                               const float* __restrict__ beta,
                                               const float* __restrict__ gamma,
                                               const float* __restrict__ biasacc,
                                               float* __restrict__ out) {
    __shared__ unsigned short Bh[8192];   // 16 KB: one kcg chunk [jt][lane][8]
    __shared__ unsigned short Bl[8192];   // 16 KB
    int tid = threadIdx.x, wave = tid >> 6, lane = tid & 63;
    int m = lane & 15, kg = lane >> 4;
    size_t rbase = (size_t)blockIdx.x * 128 + wave * 16;
    const float* xr = x + (rbase + m) * 256;   // this lane's source row

    f32x4 acc[16];
#pragma unroll
    for (int t = 0; t < 16; ++t) acc[t] = 0.f;

#pragma unroll
    for (int kcg = 0; kcg < 8; ++kcg) {
        __syncthreads();   // previous phase's B reads complete
        // stage B chunk: 16 KB hi + 16 KB lo, coalesced 16B per thread x2
#pragma unroll
        for (int v = tid; v < 1024; v += 512) {
            int jt = v >> 6, off = (v & 63) * 8;
            size_t src = (size_t)(jt * 8 + kcg) * 512 + off;
            int dst = jt * 512 + off;
            *(u16x8*)&Bh[dst] = *(const u16x8*)&Wphi[src];
            *(u16x8*)&Bl[dst] = *(const u16x8*)&Wplo[src];
        }
        // A fragment direct from global (128B line per row per kcg), RNE -> bf16
        f32x4 a0 = *(const f32x4*)&xr[kcg * 32 + kg * 8];
        f32x4 a1 = *(const f32x4*)&xr[kcg * 32 + kg * 8 + 4];
        bf16x8 ah;
#pragma unroll
        for (int e = 0; e < 4; ++e) {
            unsigned b0 = __float_as_uint(a0[e]);
            b0 += 0x7FFFu + ((b0 >> 16) & 1u);
            ah[e] = (short)(b0 >> 16);
            unsigned b1 = __float_as_uint(a1[e]);
            b1 += 0x7FFFu + ((b1 >> 16) & 1u);
            ah[4 + e] = (short)(b1 >> 16);
        }
        __syncthreads();   // B chunk visible
#pragma unroll
        for (int jt = 0; jt < 16; ++jt) {
            bf16x8 bh = *(const bf16x8*)&Bh[jt * 512 + lane * 8];
            bf16x8 bl = *(const bf16x8*)&Bl[jt * 512 + lane * 8];
            acc[jt] = MFMA16(ah, bh, acc[jt], 0, 0, 0);
            acc[jt] = MFMA16(ah, bl, acc[jt], 0, 0, 0);
        }
    }

#pragma unroll
    for (int jt = 0; jt < 16; ++jt) {
        int j = jt * 16 + m;
        float bb = beta[j] - gamma[j] * biasacc[j];
#pragma unroll
        for (int q = 0; q < 4; ++q)
            out[(rbase + kg * 4 + q) * 256 + j] = acc[jt][q] + bb;
    }
}

extern "C" void kernel_launch(void* const* d_in, const int* in_sizes, int n_in,
                              void* d_out, int out_size, void* d_ws, size_t ws_size,
                              hipStream_t stream) {
    const float* x     = (const float*)d_in[0];
    const float* gamma = (const float*)d_in[1];
    const float* beta  = (const float*)d_in[2];
    float* out  = (float*)d_out;
    float* ws   = (float*)d_ws;
    float* sums     = ws;                 // 256
    float* biasacc  = ws + 256;           // 256
    float* S8       = ws + 512;           // 8*65536
    float* Lg       = ws + 524800;        // 33280
    unsigned short* Wphi = (unsigned short*)(ws + 558080);   // 65536 bf16
    unsigned short* Wplo = (unsigned short*)(ws + 590848);   // 65536 bf16

    hipMemsetAsync(ws, 0, 524800 * sizeof(float), stream);
    hipLaunchKernelGGL(k_cov, dim3(448), dim3(512), 0, stream, x, S8, sums);
    hipLaunchKernelGGL(k_init, dim3(64), dim3(256), 0, stream, S8, sums, Lg);
    for (int kb = 0; kb < 8; ++kb) {
        hipLaunchKernelGGL(k_panel, dim3(1), dim3(512), 0, stream, Lg, kb);
        int np = TRI(7 - kb);
        if (np > 0)
            hipLaunchKernelGGL(k_trail, dim3(np), dim3(256), 0, stream, Lg, kb);
    }
    hipLaunchKernelGGL(k_inv, dim3(8), dim3(256), 0, stream, Lg, sums, gamma, Wphi, Wplo, biasacc);
    hipLaunchKernelGGL(k_apply, dim3(1568), dim3(512), 0, stream, x, Wphi, Wplo, beta, gamma, biasacc, out);
}

// Round 15
// 579.777 us; speedup vs baseline: 1.5938x; 1.0655x over previous
//
#include <hip/hip_runtime.h>
#include <hip/hip_bf16.h>
#include <math.h>

#define C 256
#define NROWS (64*56*56)   // 200704
#define EPSV 0.001f
#define TRI(i) (((i)*((i)+1))>>1)
#define NBLK 224           // k_cov blocks

typedef __attribute__((ext_vector_type(8))) short bf16x8;
typedef __attribute__((ext_vector_type(4))) float f32x4;
typedef __attribute__((ext_vector_type(4))) unsigned short u16x4;
typedef __attribute__((ext_vector_type(8))) unsigned short u16x8;
#define MFMA16 __builtin_amdgcn_mfma_f32_16x16x32_bf16

// padded packed-lower-triangle layout: row i starts at PAD(i), rows rounded to 4 floats
__device__ __forceinline__ int PAD(int i) {
    int a = i >> 2, b = i & 3;
    return ((a + 1) * (2 * a + b)) << 2;
}

__device__ __forceinline__ void split2(float v0, float v1, unsigned& hi, unsigned& lo) {
    unsigned b0 = __float_as_uint(v0), b1 = __float_as_uint(v1);
    hi = (b0 >> 16) | (b1 & 0xFFFF0000u);
    float l0 = v0 - __uint_as_float(b0 & 0xFFFF0000u);
    float l1 = v1 - __uint_as_float(b1 & 0xFFFF0000u);
    lo = (__float_as_uint(l0) >> 16) | (__float_as_uint(l1) & 0xFFFF0000u);
}

// ws layout (floats):
//  [0,256)              : channel sums
//  [256,512)            : biasacc
//  [512,33792)          : Lg = triangle (cov -> factored)
//  [33792,7832576)      : P  = per-block cov partials [224][8][17][256]  (~30 MB)
//  [7832576,+32768)     : Wphi (65536 bf16)
//  [7865344,+32768)     : Wplo

// ---------------- K2: S = X^T X via bf16-split MFMA, partials to P (no atomics) ----------------
template<int W>
__device__ __forceinline__ void cov_step(f32x4* acc, const unsigned* lh, const unsigned* ll,
                                         int m, int kg) {
    constexpr int R0 = W, R1 = 15 - W;
    constexpr int O1 = W + 1;
    bf16x8 ah[2], al[2];
    {
        int r0 = R0 * 16 + m, r1 = R1 * 16 + m;
        int o0 = r0 * 20 + ((kg ^ ((r0 >> 3) & 3)) << 2);
        int o1 = r1 * 20 + ((kg ^ ((r1 >> 3) & 3)) << 2);
        ah[0] = *(const bf16x8*)&lh[o0]; al[0] = *(const bf16x8*)&ll[o0];
        ah[1] = *(const bf16x8*)&lh[o1]; al[1] = *(const bf16x8*)&ll[o1];
    }
#pragma unroll
    for (int c = 0; c <= R1; ++c) {
        int rb = c * 16 + m;
        int ob = rb * 20 + ((kg ^ ((rb >> 3) & 3)) << 2);
        bf16x8 bh = *(const bf16x8*)&lh[ob];
        bf16x8 bl = *(const bf16x8*)&ll[ob];
        if (c <= R0) {
            acc[c] = MFMA16(ah[0], bh, acc[c], 0, 0, 0);
            acc[c] = MFMA16(ah[0], bl, acc[c], 0, 0, 0);
            acc[c] = MFMA16(al[0], bh, acc[c], 0, 0, 0);
        }
        {
            acc[O1 + c] = MFMA16(ah[1], bh, acc[O1 + c], 0, 0, 0);
            acc[O1 + c] = MFMA16(ah[1], bl, acc[O1 + c], 0, 0, 0);
            acc[O1 + c] = MFMA16(al[1], bh, acc[O1 + c], 0, 0, 0);
        }
    }
}

__global__ __launch_bounds__(512, 4) void k_cov(const float* __restrict__ x,
                                                float* __restrict__ P,
                                                float* __restrict__ sums) {
    __shared__ unsigned lh[256 * 20];    // 20 KB
    __shared__ unsigned ll_[256 * 20];   // 20 KB
    int tid = threadIdx.x, wave = tid >> 6, lane = tid & 63;
    int m = lane & 15, kg = lane >> 4;
    int ch = tid & 255, half = tid >> 8;
    const float* xc = x + (size_t)blockIdx.x * 896 * 256 + ch;
    f32x4 acc[17];
#pragma unroll
    for (int t = 0; t < 17; ++t) acc[t] = 0.f;
    float colsum = 0.f;
    int swkey = (ch >> 3) & 3;

    for (int it = 0; it < 28; ++it) {
        __syncthreads();
        const float* xr = xc + it * 32 * 256;
#pragma unroll
        for (int j = 0; j < 8; ++j) {
            int rp = half * 8 + j;
            float v0 = xr[(2 * rp) * 256];
            float v1 = xr[(2 * rp + 1) * 256];
            colsum += v0 + v1;
            unsigned h, l;
            split2(v0, v1, h, l);
            int idx = ch * 20 + ((((rp >> 2) ^ swkey) << 2) | (rp & 3));
            lh[idx] = h;
            ll_[idx] = l;
        }
        __syncthreads();
        switch (wave) {
            case 0: cov_step<0>(acc, lh, ll_, m, kg); break;
            case 1: cov_step<1>(acc, lh, ll_, m, kg); break;
            case 2: cov_step<2>(acc, lh, ll_, m, kg); break;
            case 3: cov_step<3>(acc, lh, ll_, m, kg); break;
            case 4: cov_step<4>(acc, lh, ll_, m, kg); break;
            case 5: cov_step<5>(acc, lh, ll_, m, kg); break;
            case 6: cov_step<6>(acc, lh, ll_, m, kg); break;
            default: cov_step<7>(acc, lh, ll_, m, kg); break;
        }
    }
    atomicAdd(&sums[ch], colsum);
    // plain coalesced stores of all 17 tile fragments
    float* Pb = P + ((size_t)(blockIdx.x * 8 + wave) * 17) * 256;
#pragma unroll
    for (int t = 0; t < 17; ++t)
        *(f32x4*)&Pb[t * 256 + lane * 4] = acc[t];
}

// ---------------- K3a: sum P partials -> covariance triangle in Lg ----------------
// grid = 136 blocks; block = one (W,t) chunk; threads sum over 224 blocks, coalesced.
__global__ __launch_bounds__(256) void k_init(const float* __restrict__ P,
                                              const float* __restrict__ sums,
                                              float* __restrict__ Lg) {
    int chunk = blockIdx.x;        // W*17 + t
    int W = chunk / 17, t = chunk % 17;
    int R  = (t <= W) ? W : 15 - W;
    int tj = (t <= W) ? t : t - W - 1;
    int tid = threadIdx.x;
    int lane = tid >> 2, q = tid & 3;
    int kg = lane >> 4, m = lane & 15;
    int i = R * 16 + kg * 4 + q;
    int j = tj * 16 + m;

    float s = 0.f;
    const float* p = P + (size_t)(W * 17 + t) * 256 + tid;
#pragma unroll 4
    for (int b = 0; b < NBLK; ++b)
        s += p[(size_t)b * 8 * 17 * 256];

    if (j > i) return;
    const float scale = (1.f - EPSV) / ((float)NROWS - 1.f);
    float v = (s - sums[i] * sums[j] * (1.f / (float)NROWS)) * scale;
    if (i == j) v += EPSV;
    Lg[PAD(i) + j] = v;
}

// ---------------- trailing-update helper (LDS triangle, templated NR) ----------------
template<int NR>
__device__ __forceinline__ void trail_unit(float* __restrict__ Lp, int k0,
                                           int ib2, int jb2, int r4, int c4) {
    int gj = jb2 * 32 + c4;
    int brow[4], arow[NR];
#pragma unroll
    for (int cc = 0; cc < 4; ++cc) brow[cc] = PAD(gj + cc) + k0;
#pragma unroll
    for (int rr = 0; rr < NR; ++rr) arow[rr] = PAD(ib2 * 32 + r4 + rr) + k0;
    float acc[NR][4];
#pragma unroll
    for (int rr = 0; rr < NR; ++rr)
#pragma unroll
        for (int cc = 0; cc < 4; ++cc) acc[rr][cc] = 0.f;
#pragma unroll
    for (int k4 = 0; k4 < 32; k4 += 4) {
        float4 b0 = *(const float4*)&Lp[brow[0] + k4];
        float4 b1 = *(const float4*)&Lp[brow[1] + k4];
        float4 b2 = *(const float4*)&Lp[brow[2] + k4];
        float4 b3 = *(const float4*)&Lp[brow[3] + k4];
#pragma unroll
        for (int rr = 0; rr < NR; ++rr) {
            float4 av = *(const float4*)&Lp[arow[rr] + k4];
            acc[rr][0] += av.x*b0.x + av.y*b0.y + av.z*b0.z + av.w*b0.w;
            acc[rr][1] += av.x*b1.x + av.y*b1.y + av.z*b1.z + av.w*b1.w;
            acc[rr][2] += av.x*b2.x + av.y*b2.y + av.z*b2.z + av.w*b2.w;
            acc[rr][3] += av.x*b3.x + av.y*b3.y + av.z*b3.z + av.w*b3.w;
        }
    }
    if (ib2 != jb2) {
#pragma unroll
        for (int rr = 0; rr < NR; ++rr) {
            int wb = PAD(ib2 * 32 + r4 + rr) + gj;
            float4 o = *(const float4*)&Lp[wb];
            o.x -= acc[rr][0]; o.y -= acc[rr][1]; o.z -= acc[rr][2]; o.w -= acc[rr][3];
            *(float4*)&Lp[wb] = o;
        }
    } else {
#pragma unroll
        for (int rr = 0; rr < NR; ++rr) {
            int rloc = r4 + rr;
            int wb = PAD(ib2 * 32 + rloc) + gj;
#pragma unroll
            for (int cc = 0; cc < 4; ++cc)
                if (c4 + cc <= rloc) Lp[wb + cc] -= acc[rr][cc];
        }
    }
}

// ---------------- K3b: fused factorization, single block, COMPACT code ----------------
__global__ __launch_bounds__(512, 2) void k_fact(float* __restrict__ Lg) {
    __shared__ __align__(16) float Lp[33280];   // 133.1 KB triangle
    __shared__ __align__(16) float D0[1056];    // 32x33 diag scratch
    __shared__ __align__(16) float DS[1152];    // 32x36 Dinv (zero-padded upper)
    int tid = threadIdx.x;
    int slot = tid >> 6, sub = tid & 63;
    int c4 = (sub & 7) * 4;

    for (int u = tid; u < 8320; u += 512)
        *(f32x4*)&Lp[u * 4] = *(const f32x4*)&Lg[u * 4];

    // this thread's <=2 elements of a 32x32 lower triangle (528 elems)
    int ei0, ej0, ei1 = -1, ej1 = 0;
    {
        int e = tid;
        int i = (int)((sqrtf(8.f * (float)e + 1.f) - 1.f) * 0.5f);
        while (TRI(i) > e) --i;
        while (TRI(i + 1) <= e) ++i;
        ei0 = i; ej0 = e - TRI(i);
        if (tid + 512 < 528) { ei1 = 31; ej1 = tid + 512 - TRI(31); }
    }
    __syncthreads();

    for (int kb = 0; kb < 8; ++kb) {
        int k0 = kb * 32;
        // diag block -> D0; zero DS
        D0[ei0 * 33 + ej0] = Lp[PAD(k0 + ei0) + k0 + ej0];
        if (ei1 >= 0) D0[ei1 * 33 + ej1] = Lp[PAD(k0 + ei1) + k0 + ej1];
        for (int u = tid; u < 1152; u += 512) DS[u] = 0.f;
        __syncthreads();

        // raw-column right-looking factor: 1 barrier/step, tiny loop body
        for (int k = 0; k < 32; ++k) {
            float rinv = 1.f / D0[k * 33 + k];
            bool a0 = (ej0 > k);
            bool a1 = (ei1 >= 0) && (ej1 > k);
            if (a0) D0[ei0 * 33 + ej0] -= D0[ei0 * 33 + k] * D0[ej0 * 33 + k] * rinv;
            if (a1) D0[ei1 * 33 + ej1] -= D0[ei1 * 33 + k] * D0[ej1 * 33 + k] * rinv;
            __syncthreads();
        }
        // finalize: scale columns, sqrt diagonal
        {
            float s0 = D0[ej0 * 33 + ej0];
            float s1 = (ei1 >= 0) ? D0[ej1 * 33 + ej1] : 1.f;
            __syncthreads();
            if (ei0 > ej0) D0[ei0 * 33 + ej0] *= rsqrtf(s0);
            else           D0[ei0 * 33 + ei0]  = sqrtf(s0);
            if (ei1 >= 0) {
                if (ei1 > ej1) D0[ei1 * 33 + ej1] *= rsqrtf(s1);
                else           D0[ei1 * 33 + ei1]  = sqrtf(s1);
            }
            __syncthreads();
        }
        // triangular inverse: lane c owns column c (dynamic loops, compact)
        if (tid < 32) {
            int c = tid;
            float xi = 1.f / D0[c * 33 + c];
            DS[c * 36 + c] = xi;
            Lp[PAD(k0 + c) + k0 + c] = xi;
            for (int i2 = c + 1; i2 < 32; ++i2) {
                float s = 0.f;
                for (int k = c; k < i2; ++k)
                    s += D0[i2 * 33 + k] * DS[k * 36 + c];
                float v = -s / D0[i2 * 33 + i2];
                DS[i2 * 36 + c] = v;
                Lp[PAD(k0 + i2) + k0 + c] = v;
            }
        }
        __syncthreads();

        // panel solve: L21 = A21 * Dinv^T
        {
            int mrows = 224 - k0;
            int r = tid >> 1, g = tid & 1;
            if (r < mrows) {
                int abase = PAD(k0 + 32 + r) + k0;
                float4 av[8];
#pragma unroll
                for (int q = 0; q < 8; ++q) av[q] = *(const float4*)&Lp[abase + q * 4];
#pragma unroll
                for (int tgrp = 0; tgrp < 4; ++tgrp) {
                    int cbase = g * 16 + tgrp * 4;
                    float rv[4];
#pragma unroll
                    for (int cc = 0; cc < 4; ++cc) {
                        const float* drow = &DS[(cbase + cc) * 36];
                        float s = 0.f;
#pragma unroll
                        for (int q = 0; q < 8; ++q) {
                            float4 d4 = *(const float4*)&drow[q * 4];
                            s += av[q].x*d4.x + av[q].y*d4.y + av[q].z*d4.z + av[q].w*d4.w;
                        }
                        rv[cc] = s;
                    }
                    float4 res; res.x = rv[0]; res.y = rv[1]; res.z = rv[2]; res.w = rv[3];
                    *(float4*)&Lp[abase + cbase] = res;
                }
            }
        }
        __syncthreads();

        // trailing update: A22 -= L21 L21^T, 8 wave-slots
        {
            int npairs = TRI(7 - kb);
            if (npairs > 0) {
                int lsp = (npairs >= 8) ? 0 : (npairs >= 3 ? 1 : 2);
                int splitR = 1 << lsp;
                int units = npairs << lsp;
                int rows_pu = 32 >> lsp;
                for (int u = slot; u < units; u += 8) {
                    int p = u >> lsp, rpart = u & (splitR - 1);
                    int a2 = 0;
                    while (TRI(a2 + 1) <= p) ++a2;
                    int b2 = p - TRI(a2);
                    int ib2 = kb + 1 + a2, jb2 = kb + 1 + b2;
                    int nrq = rows_pu >> 3;
                    int r4 = rpart * rows_pu + (sub >> 3) * nrq;
                    if (lsp == 0)      trail_unit<4>(Lp, k0, ib2, jb2, r4, c4);
                    else if (lsp == 1) trail_unit<2>(Lp, k0, ib2, jb2, r4, c4);
                    else               trail_unit<1>(Lp, k0, ib2, jb2, r4, c4);
                }
            }
        }
        __syncthreads();
    }

    for (int u = tid; u < 8320; u += 512)
        *(f32x4*)&Lg[u * 4] = *(const f32x4*)&Lp[u * 4];
}

// ---------------- K3c: blocked inverse + packed fragment-major bf16 epilogue ----------------
__global__ __launch_bounds__(256) void k_inv(const float* __restrict__ Lg,
                                             const float* __restrict__ sums,
                                             const float* __restrict__ gamma,
                                             unsigned short* __restrict__ Wphi,
                                             unsigned short* __restrict__ Wplo,
                                             float* __restrict__ biasacc) {
    __shared__ __align__(16) float Wcol[256][36];
    __shared__ __align__(16) float Ls[32][36];
    __shared__ __align__(16) float Tst[32][36];
    int jbb = blockIdx.x;      // 0..7 == kcg
    int tid = threadIdx.x;
    int j0 = jbb * 32;

    {
        int r = tid >> 3, cq = (tid & 7) * 4;
        const float* row = &Lg[PAD(j0 + r) + j0];
        float4 v;
        v.x = (cq     <= r) ? row[cq]     : 0.f;
        v.y = (cq + 1 <= r) ? row[cq + 1] : 0.f;
        v.z = (cq + 2 <= r) ? row[cq + 2] : 0.f;
        v.w = (cq + 3 <= r) ? row[cq + 3] : 0.f;
        *(float4*)&Wcol[j0 + r][cq] = v;
    }
    __syncthreads();

    int r2 = (tid >> 4) * 2, c2 = (tid & 15) * 2;
    for (int ib = jbb + 1; ib < 8; ++ib) {
        int i0 = ib * 32;
        float t00 = 0, t01 = 0, t10 = 0, t11 = 0;
        for (int kb = jbb; kb < ib; ++kb) {
            __syncthreads();
            {
                int r = tid >> 3, cq = (tid & 7) * 4;
                *(float4*)&Ls[r][cq] = *(const float4*)&Lg[PAD(i0 + r) + kb * 32 + cq];
            }
            __syncthreads();
            int kw = kb * 32;
#pragma unroll 8
            for (int q = 0; q < 32; ++q) {
                float l0 = Ls[r2][q], l1 = Ls[r2 + 1][q];
                float w0 = Wcol[kw + q][c2], w1 = Wcol[kw + q][c2 + 1];
                t00 += l0 * w0; t01 += l0 * w1;
                t10 += l1 * w0; t11 += l1 * w1;
            }
        }
        __syncthreads();
        Tst[r2][c2] = t00;     Tst[r2][c2 + 1] = t01;
        Tst[r2 + 1][c2] = t10; Tst[r2 + 1][c2 + 1] = t11;
        {
            int r = tid >> 3, cq = (tid & 7) * 4;
            const float* row = &Lg[PAD(i0 + r) + i0];
            float4 v;
            v.x = (cq     <= r) ? row[cq]     : 0.f;
            v.y = (cq + 1 <= r) ? row[cq + 1] : 0.f;
            v.z = (cq + 2 <= r) ? row[cq + 2] : 0.f;
            v.w = (cq + 3 <= r) ? row[cq + 3] : 0.f;
            *(float4*)&Ls[r][cq] = v;
        }
        __syncthreads();
        float w00 = 0, w01 = 0, w10 = 0, w11 = 0;
#pragma unroll 8
        for (int q = 0; q < 32; ++q) {
            float d0 = Ls[r2][q], d1 = Ls[r2 + 1][q];
            float tq0 = Tst[q][c2], tq1 = Tst[q][c2 + 1];
            w00 += d0 * tq0; w01 += d0 * tq1;
            w10 += d1 * tq0; w11 += d1 * tq1;
        }
        Wcol[i0 + r2][c2] = -w00;     Wcol[i0 + r2][c2 + 1] = -w01;
        Wcol[i0 + r2 + 1][c2] = -w10; Wcol[i0 + r2 + 1][c2 + 1] = -w11;
    }
    __syncthreads();

    {
        int r = tid;
        if (r >= j0) {
            float s = 0.f;
#pragma unroll 8
            for (int c = 0; c < 32; ++c)
                s += Wcol[r][c] * sums[j0 + c];
            atomicAdd(&biasacc[r], s * (1.f / (float)NROWS));
        }
    }
    for (int pi = tid; pi < 1024; pi += 256) {
        int jt = pi >> 6, l = pi & 63;
        int row = jt * 16 + (l & 15);
        int cb = (l >> 4) * 8;
        float g = (row >= j0) ? gamma[row] : 0.f;
        u16x4 h0, h1, lo0, lo1;
#pragma unroll
        for (int j = 0; j < 8; ++j) {
            float v = (row >= j0) ? g * Wcol[row][cb + j] : 0.f;
            unsigned b = __float_as_uint(v);
            unsigned short hi = (unsigned short)(b >> 16);
            float lf = v - __uint_as_float(b & 0xFFFF0000u);
            unsigned short lo = (unsigned short)(__float_as_uint(lf) >> 16);
            if (j < 4) { h0[j] = hi; lo0[j] = lo; }
            else       { h1[j - 4] = hi; lo1[j - 4] = lo; }
        }
        size_t base = ((size_t)(jt * 8 + jbb) * 64 + l) * 8;
        *(u16x4*)&Wphi[base]     = h0;
        *(u16x4*)&Wphi[base + 4] = h1;
        *(u16x4*)&Wplo[base]     = lo0;
        *(u16x4*)&Wplo[base + 4] = lo1;
    }
}

// ---------------- K4: out = bf16(x) * Wg^T + bias; B staged in LDS per kcg ----------------
__global__ __launch_bounds__(512) void k_apply(const float* __restrict__ x,
                                               const unsigned short* __restrict__ Wphi,
                                               const unsigned short* __restrict__ Wplo,
                                               const float* __restrict__ beta,
                                               const float* __restrict__ gamma,
                                               const float* __restrict__ biasacc,
                                               float* __restrict__ out) {
    __shared__ unsigned short Bh[8192];   // 16 KB: one kcg chunk [jt][lane][8]
    __shared__ unsigned short Bl[8192];   // 16 KB
    int tid = threadIdx.x, wave = tid >> 6, lane = tid & 63;
    int m = lane & 15, kg = lane >> 4;
    size_t rbase = (size_t)blockIdx.x * 128 + wave * 16;
    const float* xr = x + (rbase + m) * 256;

    f32x4 acc[16];
#pragma unroll
    for (int t = 0; t < 16; ++t) acc[t] = 0.f;

#pragma unroll
    for (int kcg = 0; kcg < 8; ++kcg) {
        __syncthreads();
#pragma unroll
        for (int v = tid; v < 1024; v += 512) {
            int jt = v >> 6, off = (v & 63) * 8;
            size_t src = (size_t)(jt * 8 + kcg) * 512 + off;
            int dst = jt * 512 + off;
            *(u16x8*)&Bh[dst] = *(const u16x8*)&Wphi[src];
            *(u16x8*)&Bl[dst] = *(const u16x8*)&Wplo[src];
        }
        f32x4 a0 = *(const f32x4*)&xr[kcg * 32 + kg * 8];
        f32x4 a1 = *(const f32x4*)&xr[kcg * 32 + kg * 8 + 4];
        bf16x8 ah;
#pragma unroll
        for (int e = 0; e < 4; ++e) {
            unsigned b0 = __float_as_uint(a0[e]);
            b0 += 0x7FFFu + ((b0 >> 16) & 1u);
            ah[e] = (short)(b0 >> 16);
            unsigned b1 = __float_as_uint(a1[e]);
            b1 += 0x7FFFu + ((b1 >> 16) & 1u);
            ah[4 + e] = (short)(b1 >> 16);
        }
        __syncthreads();
#pragma unroll
        for (int jt = 0; jt < 16; ++jt) {
            bf16x8 bh = *(const bf16x8*)&Bh[jt * 512 + lane * 8];
            bf16x8 bl = *(const bf16x8*)&Bl[jt * 512 + lane * 8];
            acc[jt] = MFMA16(ah, bh, acc[jt], 0, 0, 0);
            acc[jt] = MFMA16(ah, bl, acc[jt], 0, 0, 0);
        }
    }

#pragma unroll
    for (int jt = 0; jt < 16; ++jt) {
        int j = jt * 16 + m;
        float bb = beta[j] - gamma[j] * biasacc[j];
#pragma unroll
        for (int q = 0; q < 4; ++q)
            out[(rbase + kg * 4 + q) * 256 + j] = acc[jt][q] + bb;
    }
}

extern "C" void kernel_launch(void* const* d_in, const int* in_sizes, int n_in,
                              void* d_out, int out_size, void* d_ws, size_t ws_size,
                              hipStream_t stream) {
    const float* x     = (const float*)d_in[0];
    const float* gamma = (const float*)d_in[1];
    const float* beta  = (const float*)d_in[2];
    float* out  = (float*)d_out;
    float* ws   = (float*)d_ws;
    float* sums     = ws;                 // 256
    float* biasacc  = ws + 256;           // 256
    float* Lg       = ws + 512;           // 33280
    float* P        = ws + 33792;         // 224*8*17*256 = 7,798,784 floats
    unsigned short* Wphi = (unsigned short*)(ws + 7832576);  // 65536 bf16
    unsigned short* Wplo = (unsigned short*)(ws + 7865344);  // 65536 bf16

    hipMemsetAsync(ws, 0, 512 * sizeof(float), stream);
    hipLaunchKernelGGL(k_cov, dim3(NBLK), dim3(512), 0, stream, x, P, sums);
    hipLaunchKernelGGL(k_init, dim3(136), dim3(256), 0, stream, P, sums, Lg);
    hipLaunchKernelGGL(k_fact, dim3(1), dim3(512), 0, stream, Lg);
    hipLaunchKernelGGL(k_inv, dim3(8), dim3(256), 0, stream, Lg, sums, gamma, Wphi, Wplo, biasacc);
    hipLaunchKernelGGL(k_apply, dim3(1568), dim3(512), 0, stream, x, Wphi, Wplo, beta, gamma, biasacc, out);
}